// Round 4
// baseline (1436.638 us; speedup 1.0000x reference)
//
#include <hip/hip_runtime.h>
#include <hip/hip_bf16.h>
#include <hip/hip_fp16.h>
#include <math.h>

#define DH 10      // hidden dim
#define DE 3       // edge attr dim
#define DIN 3      // input dim
#define REC 20     // fp32 D record: 20 floats = 80B
#define SHU 16     // fp16 S record stride in uints: 64B-ALIGNED (10 used) -> 1 line/record
#define NSL 7      // src slices: p = src>>15 (exact); valid for N <= 229376
#define DBSH 8     // dst-bin shift: 256 dsts per bin -> nbins=782 <= 1024 CO-RESIDENT
#define DBM 255
#define BINSZ 256
#define NXCD 8     // XCDs on MI355X (m09)
#define DREC_S 21  // padded LDS stride for D-recs  (gcd(21,32)=1 -> conflict-free random dl)
#define ACC_S 11   // padded LDS stride for acc     (gcd(11,32)=1)
#define EPT 4      // edges per thread in scatter (ILP over atomic latency)
#define OVFCAP (1 << 20)   // overflow side-list capacity (1M recs, 16MB)
#define PBIN 16    // graph bins per pooling block (256 sorted nodes span <= ~4)

typedef unsigned int u32;
typedef u32 u2v __attribute__((ext_vector_type(2)));   // nontemporal-load-compatible

__device__ __forceinline__ u32 pack_h2(float a, float b) {
    union { __half2 h; u32 u; } cv;
    cv.h = __floats2half2_rn(a, b);
    return cv.u;
}
__device__ __forceinline__ float2 unpack_h2(u32 u) {
    union { u32 u; __half2 h; } cv; cv.u = u;
    return __half22float2(cv.h);
}

// ---------------------------------------------------------------------------
// Per-node records. D (fp32, dst side, biases folded). S (fp16 packed).
// ---------------------------------------------------------------------------
__device__ __forceinline__ void compute_records_h(
    const float* __restrict__ hh,
    const float* __restrict__ fW, const float* __restrict__ fb,
    const float* __restrict__ sW, const float* __restrict__ sb,
    float* __restrict__ Dout, u32* __restrict__ Sout)
{
    float fsv[DH], ssv[DH];
#pragma unroll
    for (int j = 0; j < DH; ++j) {
        float fd = fb[j], sd = sb[j], fs = 0.f, ss = 0.f;
#pragma unroll
        for (int k = 0; k < DH; ++k) {
            fd += hh[k] * fW[j*23 + k];
            fs += hh[k] * fW[j*23 + 10 + k];
            sd += hh[k] * sW[j*23 + k];
            ss += hh[k] * sW[j*23 + 10 + k];
        }
        Dout[j]      = fd;
        Dout[DH + j] = sd;
        fsv[j] = fs;
        ssv[j] = ss;
    }
#pragma unroll
    for (int j = 0; j < 5; ++j) {
        Sout[j]     = pack_h2(fsv[2*j], fsv[2*j+1]);
        Sout[5 + j] = pack_h2(ssv[2*j], ssv[2*j+1]);
    }
}

// fp32 variant for the fallback path
__device__ __forceinline__ void compute_records(
    const float* __restrict__ hh,
    const float* __restrict__ fW, const float* __restrict__ fb,
    const float* __restrict__ sW, const float* __restrict__ sb,
    float* __restrict__ Dout, float* __restrict__ Sout)
{
#pragma unroll
    for (int j = 0; j < DH; ++j) {
        float fd = fb[j], sd = sb[j], fs = 0.f, ss = 0.f;
#pragma unroll
        for (int k = 0; k < DH; ++k) {
            fd += hh[k] * fW[j*23 + k];
            fs += hh[k] * fW[j*23 + 10 + k];
            sd += hh[k] * sW[j*23 + k];
            ss += hh[k] * sW[j*23 + 10 + k];
        }
        Dout[j]      = fd;
        Dout[DH + j] = sd;
        Sout[j]      = fs;
        Sout[DH + j] = ss;
    }
}

// ---------------------------------------------------------------------------
__global__ void zero_cur(int* __restrict__ cursors, int M, int* __restrict__ ovfh,
                         float* __restrict__ gsum, float* __restrict__ gcnt, int G)
{
    int i = blockIdx.x * blockDim.x + threadIdx.x;
    if (i < M) cursors[i] = 0;
    if (i == 0) *ovfh = 0;
    if (i < G * DH) gsum[i] = 0.f;
    if (i < G) gcnt[i] = 0.f;
}

// ---------------------------------------------------------------------------
// P0: h0 = relu(x@preW.T+preb); layer-1 records
// ---------------------------------------------------------------------------
__global__ void node_pre_h(const float* __restrict__ x,
                           const float* __restrict__ preW, const float* __restrict__ preb,
                           const float* __restrict__ fW, const float* __restrict__ fb,
                           const float* __restrict__ sW, const float* __restrict__ sb,
                           float* __restrict__ h, float* __restrict__ D, u32* __restrict__ Sh,
                           int N)
{
    __shared__ float lpW[30], lpb[10], lfW[230], lfb[10], lsW[230], lsb[10];
    for (int i = threadIdx.x; i < 30;  i += blockDim.x) lpW[i] = preW[i];
    for (int i = threadIdx.x; i < 10;  i += blockDim.x) { lpb[i] = preb[i]; lfb[i] = fb[i]; lsb[i] = sb[i]; }
    for (int i = threadIdx.x; i < 230; i += blockDim.x) { lfW[i] = fW[i]; lsW[i] = sW[i]; }
    __syncthreads();

    int n = blockIdx.x * blockDim.x + threadIdx.x;
    if (n >= N) return;

    float x0 = x[(size_t)n*3], x1 = x[(size_t)n*3+1], x2 = x[(size_t)n*3+2];
    float hh[DH];
#pragma unroll
    for (int j = 0; j < DH; ++j)
        hh[j] = fmaxf(lpb[j] + x0*lpW[j*3] + x1*lpW[j*3+1] + x2*lpW[j*3+2], 0.f);

    float* hp = h + (size_t)n * DH;
#pragma unroll
    for (int j = 0; j < DH; ++j) hp[j] = hh[j];

    compute_records_h(hh, lfW, lfb, lsW, lsb, D + (size_t)n*REC, Sh + (size_t)n*SHU);
}

// ---------------------------------------------------------------------------
// Append-only bin scatter. List key = (slice p = src>>15, bin = dst>>8, xcc).
// R3 post-mortem: scatter is bound by global atomic RMW latency/throughput,
// NOT by writeback bytes. EPT=4 independent atomic->store chains per thread
// overlap the ~LLC atomic latency 4x (helps iff latency-bound; counters next
// round disambiguate). Record 8B: w0 = src15 | dst8<<15 | a2q9<<23 ; w1=h2.
// ---------------------------------------------------------------------------
__global__ void scatter_bins(const int* __restrict__ ei, const float* __restrict__ attr,
                             int* __restrict__ cursors, uint2* __restrict__ lists,
                             uint4* __restrict__ ovf, int* __restrict__ ovfh,
                             int E, int nbins, int cap)
{
    unsigned xcc;
    asm volatile("s_getreg_b32 %0, hwreg(HW_REG_XCC_ID)" : "=s"(xcc));
    xcc &= (NXCD - 1);

    int base = blockIdx.x * (256 * EPT) + threadIdx.x;
#pragma unroll
    for (int k = 0; k < EPT; ++k) {
        int e = base + k * 256;
        if (e >= E) continue;
        int src = __builtin_nontemporal_load(ei + e);
        int dst = __builtin_nontemporal_load(ei + (size_t)E + e);
        float a0 = __builtin_nontemporal_load(attr + (size_t)e * DE);
        float a1 = __builtin_nontemporal_load(attr + (size_t)e * DE + 1);
        float a2 = __builtin_nontemporal_load(attr + (size_t)e * DE + 2);

        int p   = src >> 15;
        int bin = dst >> DBSH;
        float a2c = fminf(fmaxf(a2, 0.f), 1.0f);
        u32 a2q = (u32)(a2c * 511.0f + 0.5f);
        u32 w0 = (u32)(src & 0x7FFF) | ((u32)(dst & DBM) << 15) | (a2q << 23);
        u32 w1 = pack_h2(a0, a1);

        int li = (((p * nbins) + bin) << 3) | (int)xcc;
        int pos = atomicAdd(&cursors[li], 1);
        if (pos < cap) {
            lists[(size_t)li * cap + pos] = make_uint2(w0, w1);
        } else {
            // overflow side-list keeps the OLD record format (ovf_pass unchanged)
            int op = atomicAdd(ovfh, 1);
            u32 a2q14 = (u32)(a2c * 16383.0f + 0.5f);
            if (op < OVFCAP) ovf[op] = make_uint4((u32)dst, (u32)src | (a2q14 << 18), w1, 0u);
        }
    }
}

// ---------------------------------------------------------------------------
// Gather: one wg per 256-dst bin; nbins=782 <= 1024 -> ALL BLOCKS CO-RESIDENT
// (R3 post-mortem: 1563 blocks ran in 2 generations, breaking the slice-
// lockstep L2 residency of S-records -> 208MB fetch, 419us. 782 co-resident
// blocks restore the invariant: each XCD re-reads only its 2MB S-slice.)
// D-recs + acc in LDS (padded strides, conflict-free at random dl). Edge
// reads are sequential streams; segmentation via 10 LDS float atomics/edge.
// ---------------------------------------------------------------------------
__global__ __launch_bounds__(256, 4) void gather_bins(
    const int* __restrict__ cursors, const uint2* __restrict__ lists, int cap,
    const float* __restrict__ D, const u32* __restrict__ ShU,
    const float* __restrict__ Wf, const float* __restrict__ Ws,
    float* __restrict__ accg, int N, int nbins)
{
    __shared__ float s_drec[BINSZ * DREC_S];   // 21 KB
    __shared__ float s_acc [BINSZ * ACC_S];    // 11 KB  (total 32 KB -> 4/CU)

    int bin  = blockIdx.x;
    int base = bin << DBSH;
    if (base >= N) return;
    int cn = N - base; if (cn > BINSZ) cn = BINSZ;

    for (int i = threadIdx.x; i < cn * REC; i += 256) {
        int nl = i / REC, j = i - nl * REC;
        s_drec[nl * DREC_S + j] = __builtin_nontemporal_load(D + (size_t)base * REC + i);
    }
    for (int i = threadIdx.x; i < cn * ACC_S; i += 256) s_acc[i] = 0.f;

    float wf[30], wsr[30];   // wave-uniform -> SGPRs
#pragma unroll
    for (int i = 0; i < 30; ++i) {
        int j = i / 3, t = i % 3;
        wf[i]  = Wf[j*23 + 20 + t];
        wsr[i] = Ws[j*23 + 20 + t];
    }
    __syncthreads();

    for (int p = 0; p < NSL; ++p) {
        int lbase = ((p * nbins) + bin) << 3;
        int off[9]; off[0] = 0;
#pragma unroll
        for (int x = 0; x < 8; ++x) {
            int cc = cursors[lbase + x]; if (cc > cap) cc = cap;
            off[x + 1] = off[x] + cc;
        }
        int tot = off[8];
        int pb  = p << 15;

        for (int q = threadIdx.x; q < tot; q += 256) {
            int x = 0;
#pragma unroll
            for (int k = 1; k < 8; ++k) if (q >= off[k]) x = k;
            u2v r = __builtin_nontemporal_load(
                ((const u2v*)lists) + (size_t)(lbase + x) * cap + (q - off[x]));

            int   srclow = (int)(r.x & 0x7FFFu);
            int   dl     = (int)((r.x >> 15) & (u32)DBM);
            float a2     = (float)(r.x >> 23) * (1.0f / 511.0f);
            float2 a01   = unpack_h2(r.y);
            float a0 = a01.x, a1 = a01.y;
            int   src    = pb + srclow;

            const uint4* sp = (const uint4*)(ShU + (size_t)src * SHU);
            uint4 A = sp[0];
            uint4 B = sp[1];
            uint2 C = *(const uint2*)(sp + 2);
            u32 u[10] = {A.x, A.y, A.z, A.w, B.x, B.y, B.z, B.w, C.x, C.y};

            const float* dr = s_drec + dl * DREC_S;
            float*       ac = s_acc  + dl * ACC_S;
#pragma unroll
            for (int j = 0; j < 5; ++j) {
                float2 f1 = unpack_h2(u[j]);       // fs[2j], fs[2j+1]
                float2 f2 = unpack_h2(u[5 + j]);   // ss[2j], ss[2j+1]
                {
                    const int jj = 2*j;
                    float pf = dr[jj]      + f1.x + a0*wf[jj*3]  + a1*wf[jj*3+1]  + a2*wf[jj*3+2];
                    float ps = dr[DH + jj] + f2.x + a0*wsr[jj*3] + a1*wsr[jj*3+1] + a2*wsr[jj*3+2];
                    float sg  = __builtin_amdgcn_rcpf(1.0f + __expf(-pf));
                    float sp2 = fmaxf(ps, 0.f) + __logf(1.0f + __expf(-fabsf(ps)));
                    atomicAdd(ac + jj, sg * sp2);
                }
                {
                    const int jj = 2*j + 1;
                    float pf = dr[jj]      + f1.y + a0*wf[jj*3]  + a1*wf[jj*3+1]  + a2*wf[jj*3+2];
                    float ps = dr[DH + jj] + f2.y + a0*wsr[jj*3] + a1*wsr[jj*3+1] + a2*wsr[jj*3+2];
                    float sg  = __builtin_amdgcn_rcpf(1.0f + __expf(-pf));
                    float sp2 = fmaxf(ps, 0.f) + __logf(1.0f + __expf(-fabsf(ps)));
                    atomicAdd(ac + jj, sg * sp2);
                }
            }
        }
        __syncthreads();   // keep waves slice-aligned; also fences acc before store
    }

    for (int i = threadIdx.x; i < cn * DH; i += 256) {
        int nl = i / DH, j = i - nl * DH;
        accg[(size_t)base * DH + i] = s_acc[nl * ACC_S + j];
    }
}

// ---------------------------------------------------------------------------
// Overflow pass (runs after gather_bins): ~1e2-1e4 edges, global atomics.
// ---------------------------------------------------------------------------
__global__ void ovf_pass(const uint4* __restrict__ ovf, const int* __restrict__ ovfh,
                         const float* __restrict__ D, const u32* __restrict__ ShU,
                         const float* __restrict__ Wf, const float* __restrict__ Ws,
                         float* __restrict__ accg)
{
    __shared__ float wf[30], wsr[30];
    if (threadIdx.x < 30) {
        int j = threadIdx.x / 3, t = threadIdx.x % 3;
        wf[threadIdx.x]  = Wf[j*23 + 20 + t];
        wsr[threadIdx.x] = Ws[j*23 + 20 + t];
    }
    __syncthreads();

    int oc = *ovfh; if (oc > OVFCAP) oc = OVFCAP;
    for (int i = blockIdx.x * blockDim.x + threadIdx.x; i < oc;
         i += gridDim.x * blockDim.x) {
        uint4 e = ovf[i];
        int dst = (int)e.x;
        u32 w0 = e.y;
        int src = (int)(w0 & 0x3FFFFu);
        float a2 = (float)(w0 >> 18) * (1.0f / 16383.0f);
        float2 a01 = unpack_h2(e.z);
        float a0 = a01.x, a1 = a01.y;

        float dr[REC];
        const float4* dp = (const float4*)(D + (size_t)dst * REC);
#pragma unroll
        for (int k = 0; k < 5; ++k) ((float4*)dr)[k] = dp[k];

        const uint4* sp = (const uint4*)(ShU + (size_t)src * SHU);
        uint4 A = sp[0];
        uint4 B = sp[1];
        uint2 C = *(const uint2*)(sp + 2);
        u32 u[10] = {A.x, A.y, A.z, A.w, B.x, B.y, B.z, B.w, C.x, C.y};
        float s[20];
#pragma unroll
        for (int k = 0; k < 10; ++k) {
            float2 f = unpack_h2(u[k]);
            s[2*k] = f.x; s[2*k+1] = f.y;
        }
        float* ap = accg + (size_t)dst * DH;
#pragma unroll
        for (int j = 0; j < DH; ++j) {
            float pf = dr[j]      + s[j]      + a0*wf[j*3]  + a1*wf[j*3+1]  + a2*wf[j*3+2];
            float ps = dr[DH + j] + s[DH + j] + a0*wsr[j*3] + a1*wsr[j*3+1] + a2*wsr[j*3+2];
            float sg  = __builtin_amdgcn_rcpf(1.0f + __expf(-pf));
            float sp2 = fmaxf(ps, 0.f) + __logf(1.0f + __expf(-fabsf(ps)));
            atomicAdd(ap + j, sg * sp2);
        }
    }
}

// ---------------------------------------------------------------------------
// Layer-1 epilogue: h = relu(h + acc); records for layer 2
// ---------------------------------------------------------------------------
__global__ void node_mid_h(float* __restrict__ h, const float* __restrict__ acc,
                           const float* __restrict__ fW, const float* __restrict__ fb,
                           const float* __restrict__ sW, const float* __restrict__ sb,
                           float* __restrict__ D, u32* __restrict__ Sh, int N)
{
    __shared__ float lfW[230], lfb[10], lsW[230], lsb[10];
    for (int i = threadIdx.x; i < 230; i += blockDim.x) { lfW[i] = fW[i]; lsW[i] = sW[i]; }
    for (int i = threadIdx.x; i < 10;  i += blockDim.x) { lfb[i] = fb[i]; lsb[i] = sb[i]; }
    __syncthreads();
    int n = blockIdx.x * blockDim.x + threadIdx.x;
    if (n >= N) return;
    float* hp = h + (size_t)n * DH;
    const float* ap = acc + (size_t)n * DH;
    float hh[DH];
#pragma unroll
    for (int j = 0; j < DH; ++j) {
        hh[j] = fmaxf(hp[j] + ap[j], 0.f);
        hp[j] = hh[j];
    }
    compute_records_h(hh, lfW, lfb, lsW, lsb, D + (size_t)n*REC, Sh + (size_t)n*SHU);
}

// ---------------------------------------------------------------------------
// Layer-2 epilogue + pooling: segmented block-local reduction (batch sorted).
// ---------------------------------------------------------------------------
__global__ void node_pool(const float* __restrict__ h, const float* __restrict__ acc,
                          const int* __restrict__ batch,
                          float* __restrict__ gsum, float* __restrict__ gcnt, int N)
{
    __shared__ float lg[PBIN * DH];
    __shared__ float lc[PBIN];

    int base = blockIdx.x * blockDim.x;
    int n = base + threadIdx.x;

    for (int i = threadIdx.x; i < PBIN * DH; i += blockDim.x) lg[i] = 0.f;
    if (threadIdx.x < PBIN) lc[threadIdx.x] = 0.f;
    __syncthreads();

    int b0 = batch[base];   // uniform across block (sorted)

    if (n < N) {
        int b = batch[n];
        int off = b - b0;
        const float* hp = h + (size_t)n * DH;
        const float* ap = acc + (size_t)n * DH;
        float v[DH];
#pragma unroll
        for (int j = 0; j < DH; ++j) v[j] = fmaxf(hp[j] + ap[j], 0.f);

        if (off < PBIN) {
#pragma unroll
            for (int j = 0; j < DH; ++j) atomicAdd(&lg[off * DH + j], v[j]);
            atomicAdd(&lc[off], 1.f);
        } else {   // statistically impossible (256 sorted nodes span ~4 graphs)
            float* gp = gsum + (size_t)b * DH;
#pragma unroll
            for (int j = 0; j < DH; ++j) atomicAdd(gp + j, v[j]);
            atomicAdd(gcnt + b, 1.f);
        }
    }
    __syncthreads();

    for (int i = threadIdx.x; i < PBIN * DH; i += blockDim.x) {
        int g = i / DH;
        if (lc[g] > 0.f)
            atomicAdd(&gsum[(size_t)(b0 + g) * DH + (i - g * DH)], lg[i]);
    }
    if (threadIdx.x < PBIN && lc[threadIdx.x] > 0.f)
        atomicAdd(&gcnt[b0 + threadIdx.x], lc[threadIdx.x]);
}

// ---------------------------------------------------------------------------
// Fallback path kernels (fp32 atomic path; used only if ws too small / N too big)
// ---------------------------------------------------------------------------
__global__ void node_pre_f32(const float* __restrict__ x,
                             const float* __restrict__ preW, const float* __restrict__ preb,
                             const float* __restrict__ fW, const float* __restrict__ fb,
                             const float* __restrict__ sW, const float* __restrict__ sb,
                             float* __restrict__ h, float* __restrict__ D, float* __restrict__ S,
                             float* __restrict__ agg,
                             float* __restrict__ gsum, float* __restrict__ gcnt, int N, int G)
{
    __shared__ float lpW[30], lpb[10], lfW[230], lfb[10], lsW[230], lsb[10];
    for (int i = threadIdx.x; i < 30;  i += blockDim.x) lpW[i] = preW[i];
    for (int i = threadIdx.x; i < 10;  i += blockDim.x) { lpb[i] = preb[i]; lfb[i] = fb[i]; lsb[i] = sb[i]; }
    for (int i = threadIdx.x; i < 230; i += blockDim.x) { lfW[i] = fW[i]; lsW[i] = sW[i]; }
    __syncthreads();
    int n = blockIdx.x * blockDim.x + threadIdx.x;
    if (n < G * DH) gsum[n] = 0.f;
    if (n < G)      gcnt[n] = 0.f;
    if (n >= N) return;
    float x0 = x[(size_t)n*3], x1 = x[(size_t)n*3+1], x2 = x[(size_t)n*3+2];
    float hh[DH];
#pragma unroll
    for (int j = 0; j < DH; ++j)
        hh[j] = fmaxf(lpb[j] + x0*lpW[j*3] + x1*lpW[j*3+1] + x2*lpW[j*3+2], 0.f);
    float* hp = h + (size_t)n * DH;
    float* ap = agg + (size_t)n * DH;
#pragma unroll
    for (int j = 0; j < DH; ++j) { hp[j] = hh[j]; ap[j] = 0.f; }
    compute_records(hh, lfW, lfb, lsW, lsb, D + (size_t)n*REC, S + (size_t)n*REC);
}

__global__ void edge_pass(const int* __restrict__ ei, const float* __restrict__ attr,
                          const float* __restrict__ D, const float* __restrict__ S,
                          const float* __restrict__ Wf, const float* __restrict__ Ws,
                          float* __restrict__ agg, int E)
{
    __shared__ float wfe[30], wse[30];
    if (threadIdx.x < 30) {
        int j = threadIdx.x / 3, t = threadIdx.x % 3;
        wfe[threadIdx.x] = Wf[j*23 + 20 + t];
        wse[threadIdx.x] = Ws[j*23 + 20 + t];
    }
    __syncthreads();
    int e = blockIdx.x * blockDim.x + threadIdx.x;
    if (e >= E) return;
    int src = ei[e];
    int dst = ei[(size_t)E + e];
    const float* eap = attr + (size_t)e * DE;
    float ea0 = eap[0], ea1 = eap[1], ea2 = eap[2];
    float drec[REC], srec[REC];
    const float4* Dp = (const float4*)(D + (size_t)dst * REC);
    const float4* Sp = (const float4*)(S + (size_t)src * REC);
#pragma unroll
    for (int i = 0; i < 5; ++i) { ((float4*)drec)[i] = Dp[i]; ((float4*)srec)[i] = Sp[i]; }
    float* ap = agg + (size_t)dst * DH;
#pragma unroll
    for (int j = 0; j < DH; ++j) {
        float pf = drec[j]      + srec[j]      + ea0*wfe[j*3] + ea1*wfe[j*3+1] + ea2*wfe[j*3+2];
        float ps = drec[DH + j] + srec[DH + j] + ea0*wse[j*3] + ea1*wse[j*3+1] + ea2*wse[j*3+2];
        float sg = 1.0f / (1.0f + __expf(-pf));
        float sp = fmaxf(ps, 0.f) + log1pf(__expf(-fabsf(ps)));
        atomicAdd(ap + j, sg * sp);
    }
}

__global__ void node_mid(float* __restrict__ h, float* __restrict__ agg,
                         const float* __restrict__ fW, const float* __restrict__ fb,
                         const float* __restrict__ sW, const float* __restrict__ sb,
                         float* __restrict__ D, float* __restrict__ S, int N)
{
    __shared__ float lfW[230], lfb[10], lsW[230], lsb[10];
    for (int i = threadIdx.x; i < 230; i += blockDim.x) { lfW[i] = fW[i]; lsW[i] = sW[i]; }
    for (int i = threadIdx.x; i < 10;  i += blockDim.x) { lfb[i] = fb[i]; lsb[i] = sb[i]; }
    __syncthreads();
    int n = blockIdx.x * blockDim.x + threadIdx.x;
    if (n >= N) return;
    float* hp = h + (size_t)n * DH;
    float* ap = agg + (size_t)n * DH;
    float hh[DH];
#pragma unroll
    for (int j = 0; j < DH; ++j) {
        hh[j] = fmaxf(hp[j] + ap[j], 0.f);
        hp[j] = hh[j];
        ap[j] = 0.f;
    }
    compute_records(hh, lfW, lfb, lsW, lsb, D + (size_t)n*REC, S + (size_t)n*REC);
}

__global__ void node_post(const float* __restrict__ h, const float* __restrict__ agg,
                          const int* __restrict__ batch,
                          float* __restrict__ gsum, float* __restrict__ gcnt, int N)
{
    int n = blockIdx.x * blockDim.x + threadIdx.x;
    if (n >= N) return;
    int b = batch[n];
    const float* hp = h + (size_t)n * DH;
    const float* ap = agg + (size_t)n * DH;
    float* gp = gsum + (size_t)b * DH;
#pragma unroll
    for (int j = 0; j < DH; ++j)
        atomicAdd(gp + j, fmaxf(hp[j] + ap[j], 0.f));
    atomicAdd(gcnt + b, 1.f);
}

// ---------------------------------------------------------------------------
// MLP head: one block (128 threads) per graph.
// ---------------------------------------------------------------------------
__global__ void mlp_head(const float* __restrict__ gsum, const float* __restrict__ gcnt,
                         const float* __restrict__ fc1W, const float* __restrict__ fc1b,
                         const float* __restrict__ fc2W, const float* __restrict__ fc2b,
                         const float* __restrict__ outW, const float* __restrict__ outb,
                         float* __restrict__ out, int G)
{
    __shared__ float g[DH], a1[128], a2[128];
    int gid = blockIdx.x;
    int t = threadIdx.x;
    if (t < DH) {
        float c = fmaxf(gcnt[gid], 1.0f);
        g[t] = gsum[(size_t)gid*DH + t] / c;
    }
    __syncthreads();
    {
        float acc = fc1b[t];
        const float* w = fc1W + (size_t)t * DH;
#pragma unroll
        for (int k = 0; k < DH; ++k) acc += w[k] * g[k];
        a1[t] = fmaxf(acc, 0.f);
    }
    __syncthreads();
    {
        float acc = fc2b[t];
        const float* w = fc2W + (size_t)t * 128;
#pragma unroll 8
        for (int k = 0; k < 128; ++k) acc += w[k] * a1[k];
        a2[t] = fmaxf(acc, 0.f);
    }
    __syncthreads();
    if (t < 3) {
        float acc = outb[t];
        const float* w = outW + (size_t)t * 128;
#pragma unroll 8
        for (int k = 0; k < 128; ++k) acc += w[k] * a2[k];
        out[(size_t)gid*3 + t] = acc;
    }
}

// ---------------------------------------------------------------------------
extern "C" void kernel_launch(void* const* d_in, const int* in_sizes, int n_in,
                              void* d_out, int out_size, void* d_ws, size_t ws_size,
                              hipStream_t stream)
{
    const float* x     = (const float*)d_in[0];
    const int*   ei    = (const int*)  d_in[1];
    const float* attr  = (const float*)d_in[2];
    const int*   batch = (const int*)  d_in[3];
    const float* preW  = (const float*)d_in[4];
    const float* preb  = (const float*)d_in[5];
    const float* f1W   = (const float*)d_in[6];
    const float* f1b   = (const float*)d_in[7];
    const float* s1W   = (const float*)d_in[8];
    const float* s1b   = (const float*)d_in[9];
    const float* f2W   = (const float*)d_in[10];
    const float* f2b   = (const float*)d_in[11];
    const float* s2W   = (const float*)d_in[12];
    const float* s2b   = (const float*)d_in[13];
    const float* fc1W  = (const float*)d_in[14];
    const float* fc1b  = (const float*)d_in[15];
    const float* fc2W  = (const float*)d_in[16];
    const float* fc2b  = (const float*)d_in[17];
    const float* outW  = (const float*)d_in[18];
    const float* outb  = (const float*)d_in[19];

    const int N = in_sizes[0] / DIN;          // 200000
    const int E = in_sizes[1] / 2;            // 6400000
    const int G = out_size / 3;               // 1024
    const int nbins = (N + DBM) >> DBSH;      // 782 bins of 256 dsts (CO-RESIDENT)
    const int nL = NSL * nbins * NXCD;        // 43792 lists

    const int TB = 256;
    const int nb = (N + TB - 1) / TB;
    const int seb = (E + TB * EPT - 1) / (TB * EPT);
    const int zmax = nL > G * DH ? nL : G * DH;
    const int zb = (zmax + TB - 1) / TB;

    // ---- workspace layout (list capacity computed from remaining budget) ----
    size_t f_off = 0;
    float* ws = (float*)d_ws;
    float* h    = ws + f_off; f_off += (size_t)N * DH;
    float* D    = ws + f_off; f_off += (size_t)N * REC;
    f_off = (f_off + 15) & ~(size_t)15;                        // 64B-align Sh
    u32*   Sh   = (u32*)(ws + f_off); f_off += (size_t)N * SHU;
    float* acc  = ws + f_off; f_off += (size_t)N * DH;
    float* gsum = ws + f_off; f_off += (size_t)G * DH;
    float* gcnt = ws + f_off; f_off += G;
    f_off = (f_off + 15) & ~(size_t)15;
    int* cursors = (int*)(ws + f_off); f_off += nL;
    int* ovfh    = (int*)(ws + f_off); f_off += 1;
    f_off = (f_off + 15) & ~(size_t)15;
    uint4* ovf   = (uint4*)(ws + f_off); f_off += (size_t)OVFCAP * 4;
    f_off = (f_off + 15) & ~(size_t)15;
    uint2* lists = (uint2*)(ws + f_off);

    size_t core_bytes = f_off * sizeof(float);
    long long budget = (long long)ws_size - (long long)core_bytes;
    int cap = 0;
    if (budget > 0) cap = (int)(budget / ((long long)nL * 8));
    if (cap > 256) cap = 256;
    // mean edges/list ~146 (sigma ~12): cap>=192 (+3.8 sigma) -> ovf O(1e2-1e3)

    if (cap >= 192 && N <= NSL * 32768) {
        // ===== append-bin + co-resident per-bin LDS gather path =====
        zero_cur<<<zb, TB, 0, stream>>>(cursors, nL, ovfh, gsum, gcnt, G);
        node_pre_h<<<nb, TB, 0, stream>>>(x, preW, preb, f1W, f1b, s1W, s1b,
                                          h, D, Sh, N);
        scatter_bins<<<seb, TB, 0, stream>>>(ei, attr, cursors, lists, ovf, ovfh,
                                             E, nbins, cap);

        gather_bins<<<nbins, 256, 0, stream>>>(cursors, lists, cap, D, Sh,
                                               f1W, s1W, acc, N, nbins);
        ovf_pass<<<256, 256, 0, stream>>>(ovf, ovfh, D, Sh, f1W, s1W, acc);
        node_mid_h<<<nb, TB, 0, stream>>>(h, acc, f2W, f2b, s2W, s2b, D, Sh, N);

        gather_bins<<<nbins, 256, 0, stream>>>(cursors, lists, cap, D, Sh,
                                               f2W, s2W, acc, N, nbins);
        ovf_pass<<<256, 256, 0, stream>>>(ovf, ovfh, D, Sh, f2W, s2W, acc);
        node_pool<<<nb, TB, 0, stream>>>(h, acc, batch, gsum, gcnt, N);
        mlp_head<<<G, 128, 0, stream>>>(gsum, gcnt, fc1W, fc1b, fc2W, fc2b,
                                        outW, outb, (float*)d_out, G);
    } else {
        // ===== fallback: fp32 atomic path =====
        size_t o = 0;
        float* fh    = ws + o; o += (size_t)N * DH;
        float* agg   = ws + o; o += (size_t)N * DH;
        float* fD    = ws + o; o += (size_t)N * REC;
        float* fS    = ws + o; o += (size_t)N * REC;
        float* fgsum = ws + o; o += (size_t)G * DH;
        float* fgcnt = ws + o; o += G;

        const int eb = (E + TB - 1) / TB;
        node_pre_f32<<<nb, TB, 0, stream>>>(x, preW, preb, f1W, f1b, s1W, s1b,
                                            fh, fD, fS, agg, fgsum, fgcnt, N, G);
        edge_pass<<<eb, TB, 0, stream>>>(ei, attr, fD, fS, f1W, s1W, agg, E);
        node_mid<<<nb, TB, 0, stream>>>(fh, agg, f2W, f2b, s2W, s2b, fD, fS, N);
        edge_pass<<<eb, TB, 0, stream>>>(ei, attr, fD, fS, f2W, s2W, agg, E);
        node_post<<<nb, TB, 0, stream>>>(fh, agg, batch, fgsum, fgcnt, N);
        mlp_head<<<G, 128, 0, stream>>>(fgsum, fgcnt, fc1W, fc1b, fc2W, fc2b,
                                        outW, outb, (float*)d_out, G);
    }
}

// Round 5
// 1331.524 us; speedup vs baseline: 1.0789x; 1.0789x over previous
//
#include <hip/hip_runtime.h>
#include <hip/hip_bf16.h>
#include <hip/hip_fp16.h>
#include <math.h>

#define DH 10      // hidden dim
#define DE 3       // edge attr dim
#define DIN 3      // input dim
#define REC 20     // fp32 D record: 20 floats = 80B
#define SHU 16     // fp16 S record stride in uints: 64B-ALIGNED (10 used) -> 1 line/record
#define NSL 7      // src slices: p = src>>15 (exact); valid for N <= 229376
#define DBSH 7     // dst-bin shift: 128 dsts per bin -> nbins=1563
#define DBM 127
#define BINSZ 128
#define NXCD 8     // XCDs on MI355X (m09)
#define DREC_S 21  // padded LDS stride for D-recs  (gcd(21,32)=1 -> conflict-free random dl)
#define ACC_S 11   // padded LDS stride for acc     (gcd(11,32)=1)
#define EPT 4      // edges per thread in scatter
#define OVFCAP (1 << 20)   // overflow side-list capacity (1M recs, 16MB)
#define PBIN 16    // graph bins per pooling block (256 sorted nodes span <= ~4)

typedef unsigned int u32;
typedef u32 u2v __attribute__((ext_vector_type(2)));   // nontemporal-load-compatible

__device__ __forceinline__ u32 pack_h2(float a, float b) {
    union { __half2 h; u32 u; } cv;
    cv.h = __floats2half2_rn(a, b);
    return cv.u;
}
__device__ __forceinline__ float2 unpack_h2(u32 u) {
    union { u32 u; __half2 h; } cv; cv.u = u;
    return __half22float2(cv.h);
}

// ---------------------------------------------------------------------------
// Per-node records. D (fp32, dst side, biases folded). S (fp16 packed).
// ---------------------------------------------------------------------------
__device__ __forceinline__ void compute_records_h(
    const float* __restrict__ hh,
    const float* __restrict__ fW, const float* __restrict__ fb,
    const float* __restrict__ sW, const float* __restrict__ sb,
    float* __restrict__ Dout, u32* __restrict__ Sout)
{
    float fsv[DH], ssv[DH];
#pragma unroll
    for (int j = 0; j < DH; ++j) {
        float fd = fb[j], sd = sb[j], fs = 0.f, ss = 0.f;
#pragma unroll
        for (int k = 0; k < DH; ++k) {
            fd += hh[k] * fW[j*23 + k];
            fs += hh[k] * fW[j*23 + 10 + k];
            sd += hh[k] * sW[j*23 + k];
            ss += hh[k] * sW[j*23 + 10 + k];
        }
        Dout[j]      = fd;
        Dout[DH + j] = sd;
        fsv[j] = fs;
        ssv[j] = ss;
    }
#pragma unroll
    for (int j = 0; j < 5; ++j) {
        Sout[j]     = pack_h2(fsv[2*j], fsv[2*j+1]);
        Sout[5 + j] = pack_h2(ssv[2*j], ssv[2*j+1]);
    }
}

// fp32 variant for the fallback path
__device__ __forceinline__ void compute_records(
    const float* __restrict__ hh,
    const float* __restrict__ fW, const float* __restrict__ fb,
    const float* __restrict__ sW, const float* __restrict__ sb,
    float* __restrict__ Dout, float* __restrict__ Sout)
{
#pragma unroll
    for (int j = 0; j < DH; ++j) {
        float fd = fb[j], sd = sb[j], fs = 0.f, ss = 0.f;
#pragma unroll
        for (int k = 0; k < DH; ++k) {
            fd += hh[k] * fW[j*23 + k];
            fs += hh[k] * fW[j*23 + 10 + k];
            sd += hh[k] * sW[j*23 + k];
            ss += hh[k] * sW[j*23 + 10 + k];
        }
        Dout[j]      = fd;
        Dout[DH + j] = sd;
        Sout[j]      = fs;
        Sout[DH + j] = ss;
    }
}

// ---------------------------------------------------------------------------
__global__ void zero_cur(int* __restrict__ cursors, int M, int* __restrict__ ovfh,
                         float* __restrict__ gsum, float* __restrict__ gcnt, int G)
{
    int i = blockIdx.x * blockDim.x + threadIdx.x;
    if (i < M) cursors[i] = 0;
    if (i == 0) *ovfh = 0;
    if (i < G * DH) gsum[i] = 0.f;
    if (i < G) gcnt[i] = 0.f;
}

// ---------------------------------------------------------------------------
// P0: h0 = relu(x@preW.T+preb); layer-1 records
// ---------------------------------------------------------------------------
__global__ void node_pre_h(const float* __restrict__ x,
                           const float* __restrict__ preW, const float* __restrict__ preb,
                           const float* __restrict__ fW, const float* __restrict__ fb,
                           const float* __restrict__ sW, const float* __restrict__ sb,
                           float* __restrict__ h, float* __restrict__ D, u32* __restrict__ Sh,
                           int N)
{
    __shared__ float lpW[30], lpb[10], lfW[230], lfb[10], lsW[230], lsb[10];
    for (int i = threadIdx.x; i < 30;  i += blockDim.x) lpW[i] = preW[i];
    for (int i = threadIdx.x; i < 10;  i += blockDim.x) { lpb[i] = preb[i]; lfb[i] = fb[i]; lsb[i] = sb[i]; }
    for (int i = threadIdx.x; i < 230; i += blockDim.x) { lfW[i] = fW[i]; lsW[i] = sW[i]; }
    __syncthreads();

    int n = blockIdx.x * blockDim.x + threadIdx.x;
    if (n >= N) return;

    float x0 = x[(size_t)n*3], x1 = x[(size_t)n*3+1], x2 = x[(size_t)n*3+2];
    float hh[DH];
#pragma unroll
    for (int j = 0; j < DH; ++j)
        hh[j] = fmaxf(lpb[j] + x0*lpW[j*3] + x1*lpW[j*3+1] + x2*lpW[j*3+2], 0.f);

    float* hp = h + (size_t)n * DH;
#pragma unroll
    for (int j = 0; j < DH; ++j) hp[j] = hh[j];

    compute_records_h(hh, lfW, lfb, lsW, lsb, D + (size_t)n*REC, Sh + (size_t)n*SHU);
}

// ---------------------------------------------------------------------------
// Append-only bin scatter. List key index = xcc*snb + p*nbins + bin
// (xcc-MAJOR: the 8 per-XCD cursors of one (p,bin) no longer share a 64B
// line -> no cross-XCD atomic line ping-pong). Scatter is at the device
// atomic RMW wall (~8/cyc); EPT=4 gives ILP over atomic latency.
// Record 8B: w0 = src15 | dst7<<15 | a2q10<<22 ; w1 = h2(a0,a1).
// ---------------------------------------------------------------------------
__global__ void scatter_bins(const int* __restrict__ ei, const float* __restrict__ attr,
                             int* __restrict__ cursors, uint2* __restrict__ lists,
                             uint4* __restrict__ ovf, int* __restrict__ ovfh,
                             int E, int nbins, int cap)
{
    unsigned xcc;
    asm volatile("s_getreg_b32 %0, hwreg(HW_REG_XCC_ID)" : "=s"(xcc));
    xcc &= (NXCD - 1);
    int snb = NSL * nbins;

    int base = blockIdx.x * (256 * EPT) + threadIdx.x;
#pragma unroll
    for (int k = 0; k < EPT; ++k) {
        int e = base + k * 256;
        if (e >= E) continue;
        int src = __builtin_nontemporal_load(ei + e);
        int dst = __builtin_nontemporal_load(ei + (size_t)E + e);
        float a0 = __builtin_nontemporal_load(attr + (size_t)e * DE);
        float a1 = __builtin_nontemporal_load(attr + (size_t)e * DE + 1);
        float a2 = __builtin_nontemporal_load(attr + (size_t)e * DE + 2);

        int p   = src >> 15;
        int bin = dst >> DBSH;
        float a2c = fminf(fmaxf(a2, 0.f), 1.0f);
        u32 a2q = (u32)(a2c * 1023.0f + 0.5f);
        u32 w0 = (u32)(src & 0x7FFF) | ((u32)(dst & DBM) << 15) | (a2q << 22);
        u32 w1 = pack_h2(a0, a1);

        int li = (int)xcc * snb + p * nbins + bin;
        int pos = atomicAdd(&cursors[li], 1);
        if (pos < cap) {
            lists[(size_t)li * cap + pos] = make_uint2(w0, w1);
        } else {
            // overflow side-list keeps the OLD record format (ovf_pass unchanged)
            int op = atomicAdd(ovfh, 1);
            u32 a2q14 = (u32)(a2c * 16383.0f + 0.5f);
            if (op < OVFCAP) ovf[op] = make_uint4((u32)dst, (u32)src | (a2q14 << 18), w1, 0u);
        }
    }
}

// ---------------------------------------------------------------------------
// Gather: one wg per 128-dst bin; 16 KB LDS + launch_bounds(256,8) ->
// capacity 8 blk/CU x 256 CU = 2048 >= 1563 bins: ALL co-resident (single
// generation, slice-lockstep, S-slice L2-resident) AND ~24 waves/CU to hide
// the record->S dependent-load chain (R4 post-mortem: 8 waves/CU at 32KB LDS
// was latency-starved). 2-way edge ILP: both list-records and both 64B
// S-records issue before either compute (tail: clamp 2nd index, predicate
// only its LDS atomics).
// ---------------------------------------------------------------------------
__global__ __launch_bounds__(256, 8) void gather_bins(
    const int* __restrict__ cursors, const uint2* __restrict__ lists, int cap,
    const float* __restrict__ D, const u32* __restrict__ ShU,
    const float* __restrict__ Wf, const float* __restrict__ Ws,
    float* __restrict__ accg, int N, int nbins)
{
    __shared__ float s_drec[BINSZ * DREC_S];   // 10.50 KB
    __shared__ float s_acc [BINSZ * ACC_S];    //  5.63 KB  (16 KB total -> 8/CU)

    int bin  = blockIdx.x;
    int base = bin << DBSH;
    if (base >= N) return;
    int cn = N - base; if (cn > BINSZ) cn = BINSZ;
    int snb = NSL * nbins;
    const u2v* listsv = (const u2v*)lists;

    for (int i = threadIdx.x; i < cn * REC; i += 256) {
        int nl = i / REC, j = i - nl * REC;
        s_drec[nl * DREC_S + j] = __builtin_nontemporal_load(D + (size_t)base * REC + i);
    }
    for (int i = threadIdx.x; i < cn * ACC_S; i += 256) s_acc[i] = 0.f;

    float wf[30], wsr[30];   // wave-uniform -> SGPRs
#pragma unroll
    for (int i = 0; i < 30; ++i) {
        int j = i / 3, t = i % 3;
        wf[i]  = Wf[j*23 + 20 + t];
        wsr[i] = Ws[j*23 + 20 + t];
    }
    __syncthreads();

    for (int p = 0; p < NSL; ++p) {
        int pnb = p * nbins + bin;
        int off[9]; off[0] = 0;
        size_t bx[8];
#pragma unroll
        for (int x = 0; x < 8; ++x) {
            int cc = cursors[(size_t)x * snb + pnb]; if (cc > cap) cc = cap;
            off[x + 1] = off[x] + cc;
            bx[x] = (size_t)((size_t)x * snb + pnb) * cap - (size_t)off[x];
        }
        int tot = off[8];
        int pb  = p << 15;

        for (int q = threadIdx.x; q < tot; q += 512) {
            int q2  = q + 256;
            bool has2 = (q2 < tot);
            int q2c = has2 ? q2 : q;

            // ---- locate + load both list records ----
            size_t a1 = bx[0];
#pragma unroll
            for (int k = 1; k < 8; ++k) if (q  >= off[k]) a1 = bx[k];
            size_t a2a = bx[0];
#pragma unroll
            for (int k = 1; k < 8; ++k) if (q2c >= off[k]) a2a = bx[k];
            u2v r1 = __builtin_nontemporal_load(listsv + a1  + q);
            u2v r2 = __builtin_nontemporal_load(listsv + a2a + q2c);

            // ---- decode both, issue both S loads ----
            int   src1 = pb + (int)(r1.x & 0x7FFFu);
            int   dl1  = (int)((r1.x >> 15) & (u32)DBM);
            float a2f1 = (float)(r1.x >> 22) * (1.0f / 1023.0f);
            float2 a011 = unpack_h2(r1.y);
            int   src2 = pb + (int)(r2.x & 0x7FFFu);
            int   dl2  = (int)((r2.x >> 15) & (u32)DBM);
            float a2f2 = (float)(r2.x >> 22) * (1.0f / 1023.0f);
            float2 a012 = unpack_h2(r2.y);

            const uint4* sp1 = (const uint4*)(ShU + (size_t)src1 * SHU);
            const uint4* sp2 = (const uint4*)(ShU + (size_t)src2 * SHU);
            uint4 A1 = sp1[0];
            uint4 B1 = sp1[1];
            uint2 C1 = *(const uint2*)(sp1 + 2);
            uint4 A2 = sp2[0];
            uint4 B2 = sp2[1];
            uint2 C2 = *(const uint2*)(sp2 + 2);

            // ---- compute edge 1 ----
            {
                u32 u[10] = {A1.x, A1.y, A1.z, A1.w, B1.x, B1.y, B1.z, B1.w, C1.x, C1.y};
                const float* dr = s_drec + dl1 * DREC_S;
                float*       ac = s_acc  + dl1 * ACC_S;
                float a0 = a011.x, a1f = a011.y, a2 = a2f1;
#pragma unroll
                for (int j = 0; j < 5; ++j) {
                    float2 f1 = unpack_h2(u[j]);
                    float2 f2 = unpack_h2(u[5 + j]);
                    {
                        const int jj = 2*j;
                        float pf = dr[jj]      + f1.x + a0*wf[jj*3]  + a1f*wf[jj*3+1]  + a2*wf[jj*3+2];
                        float ps = dr[DH + jj] + f2.x + a0*wsr[jj*3] + a1f*wsr[jj*3+1] + a2*wsr[jj*3+2];
                        float sg  = __builtin_amdgcn_rcpf(1.0f + __expf(-pf));
                        float sp2v = fmaxf(ps, 0.f) + __logf(1.0f + __expf(-fabsf(ps)));
                        atomicAdd(ac + jj, sg * sp2v);
                    }
                    {
                        const int jj = 2*j + 1;
                        float pf = dr[jj]      + f1.y + a0*wf[jj*3]  + a1f*wf[jj*3+1]  + a2*wf[jj*3+2];
                        float ps = dr[DH + jj] + f2.y + a0*wsr[jj*3] + a1f*wsr[jj*3+1] + a2*wsr[jj*3+2];
                        float sg  = __builtin_amdgcn_rcpf(1.0f + __expf(-pf));
                        float sp2v = fmaxf(ps, 0.f) + __logf(1.0f + __expf(-fabsf(ps)));
                        atomicAdd(ac + jj, sg * sp2v);
                    }
                }
            }
            // ---- compute edge 2 (arithmetic unconditional; LDS adds predicated) ----
            {
                u32 u[10] = {A2.x, A2.y, A2.z, A2.w, B2.x, B2.y, B2.z, B2.w, C2.x, C2.y};
                const float* dr = s_drec + dl2 * DREC_S;
                float*       ac = s_acc  + dl2 * ACC_S;
                float a0 = a012.x, a1f = a012.y, a2 = a2f2;
#pragma unroll
                for (int j = 0; j < 5; ++j) {
                    float2 f1 = unpack_h2(u[j]);
                    float2 f2 = unpack_h2(u[5 + j]);
                    {
                        const int jj = 2*j;
                        float pf = dr[jj]      + f1.x + a0*wf[jj*3]  + a1f*wf[jj*3+1]  + a2*wf[jj*3+2];
                        float ps = dr[DH + jj] + f2.x + a0*wsr[jj*3] + a1f*wsr[jj*3+1] + a2*wsr[jj*3+2];
                        float sg  = __builtin_amdgcn_rcpf(1.0f + __expf(-pf));
                        float sp2v = fmaxf(ps, 0.f) + __logf(1.0f + __expf(-fabsf(ps)));
                        if (has2) atomicAdd(ac + jj, sg * sp2v);
                    }
                    {
                        const int jj = 2*j + 1;
                        float pf = dr[jj]      + f1.y + a0*wf[jj*3]  + a1f*wf[jj*3+1]  + a2*wf[jj*3+2];
                        float ps = dr[DH + jj] + f2.y + a0*wsr[jj*3] + a1f*wsr[jj*3+1] + a2*wsr[jj*3+2];
                        float sg  = __builtin_amdgcn_rcpf(1.0f + __expf(-pf));
                        float sp2v = fmaxf(ps, 0.f) + __logf(1.0f + __expf(-fabsf(ps)));
                        if (has2) atomicAdd(ac + jj, sg * sp2v);
                    }
                }
            }
        }
        __syncthreads();   // keep waves slice-aligned; also fences acc before store
    }

    for (int i = threadIdx.x; i < cn * DH; i += 256) {
        int nl = i / DH, j = i - nl * DH;
        accg[(size_t)base * DH + i] = s_acc[nl * ACC_S + j];
    }
}

// ---------------------------------------------------------------------------
// Overflow pass (runs after gather_bins): ~1e2-1e4 edges, global atomics.
// ---------------------------------------------------------------------------
__global__ void ovf_pass(const uint4* __restrict__ ovf, const int* __restrict__ ovfh,
                         const float* __restrict__ D, const u32* __restrict__ ShU,
                         const float* __restrict__ Wf, const float* __restrict__ Ws,
                         float* __restrict__ accg)
{
    __shared__ float wf[30], wsr[30];
    if (threadIdx.x < 30) {
        int j = threadIdx.x / 3, t = threadIdx.x % 3;
        wf[threadIdx.x]  = Wf[j*23 + 20 + t];
        wsr[threadIdx.x] = Ws[j*23 + 20 + t];
    }
    __syncthreads();

    int oc = *ovfh; if (oc > OVFCAP) oc = OVFCAP;
    for (int i = blockIdx.x * blockDim.x + threadIdx.x; i < oc;
         i += gridDim.x * blockDim.x) {
        uint4 e = ovf[i];
        int dst = (int)e.x;
        u32 w0 = e.y;
        int src = (int)(w0 & 0x3FFFFu);
        float a2 = (float)(w0 >> 18) * (1.0f / 16383.0f);
        float2 a01 = unpack_h2(e.z);
        float a0 = a01.x, a1 = a01.y;

        float dr[REC];
        const float4* dp = (const float4*)(D + (size_t)dst * REC);
#pragma unroll
        for (int k = 0; k < 5; ++k) ((float4*)dr)[k] = dp[k];

        const uint4* sp = (const uint4*)(ShU + (size_t)src * SHU);
        uint4 A = sp[0];
        uint4 B = sp[1];
        uint2 C = *(const uint2*)(sp + 2);
        u32 u[10] = {A.x, A.y, A.z, A.w, B.x, B.y, B.z, B.w, C.x, C.y};
        float s[20];
#pragma unroll
        for (int k = 0; k < 10; ++k) {
            float2 f = unpack_h2(u[k]);
            s[2*k] = f.x; s[2*k+1] = f.y;
        }
        float* ap = accg + (size_t)dst * DH;
#pragma unroll
        for (int j = 0; j < DH; ++j) {
            float pf = dr[j]      + s[j]      + a0*wf[j*3]  + a1*wf[j*3+1]  + a2*wf[j*3+2];
            float ps = dr[DH + j] + s[DH + j] + a0*wsr[j*3] + a1*wsr[j*3+1] + a2*wsr[j*3+2];
            float sg  = __builtin_amdgcn_rcpf(1.0f + __expf(-pf));
            float sp2 = fmaxf(ps, 0.f) + __logf(1.0f + __expf(-fabsf(ps)));
            atomicAdd(ap + j, sg * sp2);
        }
    }
}

// ---------------------------------------------------------------------------
// Layer-1 epilogue: h = relu(h + acc); records for layer 2
// ---------------------------------------------------------------------------
__global__ void node_mid_h(float* __restrict__ h, const float* __restrict__ acc,
                           const float* __restrict__ fW, const float* __restrict__ fb,
                           const float* __restrict__ sW, const float* __restrict__ sb,
                           float* __restrict__ D, u32* __restrict__ Sh, int N)
{
    __shared__ float lfW[230], lfb[10], lsW[230], lsb[10];
    for (int i = threadIdx.x; i < 230; i += blockDim.x) { lfW[i] = fW[i]; lsW[i] = sW[i]; }
    for (int i = threadIdx.x; i < 10;  i += blockDim.x) { lfb[i] = fb[i]; lsb[i] = sb[i]; }
    __syncthreads();
    int n = blockIdx.x * blockDim.x + threadIdx.x;
    if (n >= N) return;
    float* hp = h + (size_t)n * DH;
    const float* ap = acc + (size_t)n * DH;
    float hh[DH];
#pragma unroll
    for (int j = 0; j < DH; ++j) {
        hh[j] = fmaxf(hp[j] + ap[j], 0.f);
        hp[j] = hh[j];
    }
    compute_records_h(hh, lfW, lfb, lsW, lsb, D + (size_t)n*REC, Sh + (size_t)n*SHU);
}

// ---------------------------------------------------------------------------
// Layer-2 epilogue + pooling: segmented block-local reduction (batch sorted).
// ---------------------------------------------------------------------------
__global__ void node_pool(const float* __restrict__ h, const float* __restrict__ acc,
                          const int* __restrict__ batch,
                          float* __restrict__ gsum, float* __restrict__ gcnt, int N)
{
    __shared__ float lg[PBIN * DH];
    __shared__ float lc[PBIN];

    int base = blockIdx.x * blockDim.x;
    int n = base + threadIdx.x;

    for (int i = threadIdx.x; i < PBIN * DH; i += blockDim.x) lg[i] = 0.f;
    if (threadIdx.x < PBIN) lc[threadIdx.x] = 0.f;
    __syncthreads();

    int b0 = batch[base];   // uniform across block (sorted)

    if (n < N) {
        int b = batch[n];
        int off = b - b0;
        const float* hp = h + (size_t)n * DH;
        const float* ap = acc + (size_t)n * DH;
        float v[DH];
#pragma unroll
        for (int j = 0; j < DH; ++j) v[j] = fmaxf(hp[j] + ap[j], 0.f);

        if (off < PBIN) {
#pragma unroll
            for (int j = 0; j < DH; ++j) atomicAdd(&lg[off * DH + j], v[j]);
            atomicAdd(&lc[off], 1.f);
        } else {   // statistically impossible (256 sorted nodes span ~4 graphs)
            float* gp = gsum + (size_t)b * DH;
#pragma unroll
            for (int j = 0; j < DH; ++j) atomicAdd(gp + j, v[j]);
            atomicAdd(gcnt + b, 1.f);
        }
    }
    __syncthreads();

    for (int i = threadIdx.x; i < PBIN * DH; i += blockDim.x) {
        int g = i / DH;
        if (lc[g] > 0.f)
            atomicAdd(&gsum[(size_t)(b0 + g) * DH + (i - g * DH)], lg[i]);
    }
    if (threadIdx.x < PBIN && lc[threadIdx.x] > 0.f)
        atomicAdd(&gcnt[b0 + threadIdx.x], lc[threadIdx.x]);
}

// ---------------------------------------------------------------------------
// Fallback path kernels (fp32 atomic path; used only if ws too small / N too big)
// ---------------------------------------------------------------------------
__global__ void node_pre_f32(const float* __restrict__ x,
                             const float* __restrict__ preW, const float* __restrict__ preb,
                             const float* __restrict__ fW, const float* __restrict__ fb,
                             const float* __restrict__ sW, const float* __restrict__ sb,
                             float* __restrict__ h, float* __restrict__ D, float* __restrict__ S,
                             float* __restrict__ agg,
                             float* __restrict__ gsum, float* __restrict__ gcnt, int N, int G)
{
    __shared__ float lpW[30], lpb[10], lfW[230], lfb[10], lsW[230], lsb[10];
    for (int i = threadIdx.x; i < 30;  i += blockDim.x) lpW[i] = preW[i];
    for (int i = threadIdx.x; i < 10;  i += blockDim.x) { lpb[i] = preb[i]; lfb[i] = fb[i]; lsb[i] = sb[i]; }
    for (int i = threadIdx.x; i < 230; i += blockDim.x) { lfW[i] = fW[i]; lsW[i] = sW[i]; }
    __syncthreads();
    int n = blockIdx.x * blockDim.x + threadIdx.x;
    if (n < G * DH) gsum[n] = 0.f;
    if (n < G)      gcnt[n] = 0.f;
    if (n >= N) return;
    float x0 = x[(size_t)n*3], x1 = x[(size_t)n*3+1], x2 = x[(size_t)n*3+2];
    float hh[DH];
#pragma unroll
    for (int j = 0; j < DH; ++j)
        hh[j] = fmaxf(lpb[j] + x0*lpW[j*3] + x1*lpW[j*3+1] + x2*lpW[j*3+2], 0.f);
    float* hp = h + (size_t)n * DH;
    float* ap = agg + (size_t)n * DH;
#pragma unroll
    for (int j = 0; j < DH; ++j) { hp[j] = hh[j]; ap[j] = 0.f; }
    compute_records(hh, lfW, lfb, lsW, lsb, D + (size_t)n*REC, S + (size_t)n*REC);
}

__global__ void edge_pass(const int* __restrict__ ei, const float* __restrict__ attr,
                          const float* __restrict__ D, const float* __restrict__ S,
                          const float* __restrict__ Wf, const float* __restrict__ Ws,
                          float* __restrict__ agg, int E)
{
    __shared__ float wfe[30], wse[30];
    if (threadIdx.x < 30) {
        int j = threadIdx.x / 3, t = threadIdx.x % 3;
        wfe[threadIdx.x] = Wf[j*23 + 20 + t];
        wse[threadIdx.x] = Ws[j*23 + 20 + t];
    }
    __syncthreads();
    int e = blockIdx.x * blockDim.x + threadIdx.x;
    if (e >= E) return;
    int src = ei[e];
    int dst = ei[(size_t)E + e];
    const float* eap = attr + (size_t)e * DE;
    float ea0 = eap[0], ea1 = eap[1], ea2 = eap[2];
    float drec[REC], srec[REC];
    const float4* Dp = (const float4*)(D + (size_t)dst * REC);
    const float4* Sp = (const float4*)(S + (size_t)src * REC);
#pragma unroll
    for (int i = 0; i < 5; ++i) { ((float4*)drec)[i] = Dp[i]; ((float4*)srec)[i] = Sp[i]; }
    float* ap = agg + (size_t)dst * DH;
#pragma unroll
    for (int j = 0; j < DH; ++j) {
        float pf = drec[j]      + srec[j]      + ea0*wfe[j*3] + ea1*wfe[j*3+1] + ea2*wfe[j*3+2];
        float ps = drec[DH + j] + srec[DH + j] + ea0*wse[j*3] + ea1*wse[j*3+1] + ea2*wse[j*3+2];
        float sg = 1.0f / (1.0f + __expf(-pf));
        float sp = fmaxf(ps, 0.f) + log1pf(__expf(-fabsf(ps)));
        atomicAdd(ap + j, sg * sp);
    }
}

__global__ void node_mid(float* __restrict__ h, float* __restrict__ agg,
                         const float* __restrict__ fW, const float* __restrict__ fb,
                         const float* __restrict__ sW, const float* __restrict__ sb,
                         float* __restrict__ D, float* __restrict__ S, int N)
{
    __shared__ float lfW[230], lfb[10], lsW[230], lsb[10];
    for (int i = threadIdx.x; i < 230; i += blockDim.x) { lfW[i] = fW[i]; lsW[i] = sW[i]; }
    for (int i = threadIdx.x; i < 10;  i += blockDim.x) { lfb[i] = fb[i]; lsb[i] = sb[i]; }
    __syncthreads();
    int n = blockIdx.x * blockDim.x + threadIdx.x;
    if (n >= N) return;
    float* hp = h + (size_t)n * DH;
    float* ap = agg + (size_t)n * DH;
    float hh[DH];
#pragma unroll
    for (int j = 0; j < DH; ++j) {
        hh[j] = fmaxf(hp[j] + ap[j], 0.f);
        hp[j] = hh[j];
        ap[j] = 0.f;
    }
    compute_records(hh, lfW, lfb, lsW, lsb, D + (size_t)n*REC, S + (size_t)n*REC);
}

__global__ void node_post(const float* __restrict__ h, const float* __restrict__ agg,
                          const int* __restrict__ batch,
                          float* __restrict__ gsum, float* __restrict__ gcnt, int N)
{
    int n = blockIdx.x * blockDim.x + threadIdx.x;
    if (n >= N) return;
    int b = batch[n];
    const float* hp = h + (size_t)n * DH;
    const float* ap = agg + (size_t)n * DH;
    float* gp = gsum + (size_t)b * DH;
#pragma unroll
    for (int j = 0; j < DH; ++j)
        atomicAdd(gp + j, fmaxf(hp[j] + ap[j], 0.f));
    atomicAdd(gcnt + b, 1.f);
}

// ---------------------------------------------------------------------------
// MLP head: one block (128 threads) per graph.
// ---------------------------------------------------------------------------
__global__ void mlp_head(const float* __restrict__ gsum, const float* __restrict__ gcnt,
                         const float* __restrict__ fc1W, const float* __restrict__ fc1b,
                         const float* __restrict__ fc2W, const float* __restrict__ fc2b,
                         const float* __restrict__ outW, const float* __restrict__ outb,
                         float* __restrict__ out, int G)
{
    __shared__ float g[DH], a1[128], a2[128];
    int gid = blockIdx.x;
    int t = threadIdx.x;
    if (t < DH) {
        float c = fmaxf(gcnt[gid], 1.0f);
        g[t] = gsum[(size_t)gid*DH + t] / c;
    }
    __syncthreads();
    {
        float acc = fc1b[t];
        const float* w = fc1W + (size_t)t * DH;
#pragma unroll
        for (int k = 0; k < DH; ++k) acc += w[k] * g[k];
        a1[t] = fmaxf(acc, 0.f);
    }
    __syncthreads();
    {
        float acc = fc2b[t];
        const float* w = fc2W + (size_t)t * 128;
#pragma unroll 8
        for (int k = 0; k < 128; ++k) acc += w[k] * a1[k];
        a2[t] = fmaxf(acc, 0.f);
    }
    __syncthreads();
    if (t < 3) {
        float acc = outb[t];
        const float* w = outW + (size_t)t * 128;
#pragma unroll 8
        for (int k = 0; k < 128; ++k) acc += w[k] * a2[k];
        out[(size_t)gid*3 + t] = acc;
    }
}

// ---------------------------------------------------------------------------
extern "C" void kernel_launch(void* const* d_in, const int* in_sizes, int n_in,
                              void* d_out, int out_size, void* d_ws, size_t ws_size,
                              hipStream_t stream)
{
    const float* x     = (const float*)d_in[0];
    const int*   ei    = (const int*)  d_in[1];
    const float* attr  = (const float*)d_in[2];
    const int*   batch = (const int*)  d_in[3];
    const float* preW  = (const float*)d_in[4];
    const float* preb  = (const float*)d_in[5];
    const float* f1W   = (const float*)d_in[6];
    const float* f1b   = (const float*)d_in[7];
    const float* s1W   = (const float*)d_in[8];
    const float* s1b   = (const float*)d_in[9];
    const float* f2W   = (const float*)d_in[10];
    const float* f2b   = (const float*)d_in[11];
    const float* s2W   = (const float*)d_in[12];
    const float* s2b   = (const float*)d_in[13];
    const float* fc1W  = (const float*)d_in[14];
    const float* fc1b  = (const float*)d_in[15];
    const float* fc2W  = (const float*)d_in[16];
    const float* fc2b  = (const float*)d_in[17];
    const float* outW  = (const float*)d_in[18];
    const float* outb  = (const float*)d_in[19];

    const int N = in_sizes[0] / DIN;          // 200000
    const int E = in_sizes[1] / 2;            // 6400000
    const int G = out_size / 3;               // 1024
    const int nbins = (N + DBM) >> DBSH;      // 1563 bins of 128 dsts
    const int nL = NSL * nbins * NXCD;        // 87528 lists

    const int TB = 256;
    const int nb = (N + TB - 1) / TB;
    const int seb = (E + TB * EPT - 1) / (TB * EPT);
    const int zmax = nL > G * DH ? nL : G * DH;
    const int zb = (zmax + TB - 1) / TB;

    // ---- workspace layout (list capacity computed from remaining budget) ----
    size_t f_off = 0;
    float* ws = (float*)d_ws;
    float* h    = ws + f_off; f_off += (size_t)N * DH;
    float* D    = ws + f_off; f_off += (size_t)N * REC;
    f_off = (f_off + 15) & ~(size_t)15;                        // 64B-align Sh
    u32*   Sh   = (u32*)(ws + f_off); f_off += (size_t)N * SHU;
    float* acc  = ws + f_off; f_off += (size_t)N * DH;
    float* gsum = ws + f_off; f_off += (size_t)G * DH;
    float* gcnt = ws + f_off; f_off += G;
    f_off = (f_off + 15) & ~(size_t)15;
    int* cursors = (int*)(ws + f_off); f_off += nL;
    int* ovfh    = (int*)(ws + f_off); f_off += 1;
    f_off = (f_off + 15) & ~(size_t)15;
    uint4* ovf   = (uint4*)(ws + f_off); f_off += (size_t)OVFCAP * 4;
    f_off = (f_off + 15) & ~(size_t)15;
    uint2* lists = (uint2*)(ws + f_off);

    size_t core_bytes = f_off * sizeof(float);
    long long budget = (long long)ws_size - (long long)core_bytes;
    int cap = 0;
    if (budget > 0) cap = (int)(budget / ((long long)nL * 8));
    if (cap > 128) cap = 128;
    // mean edges/list ~73 (sigma ~8.5): cap>=104 keeps overflow to O(1e2-1e3)

    if (cap >= 104 && N <= NSL * 32768) {
        // ===== append-bin + co-resident high-occupancy gather path =====
        zero_cur<<<zb, TB, 0, stream>>>(cursors, nL, ovfh, gsum, gcnt, G);
        node_pre_h<<<nb, TB, 0, stream>>>(x, preW, preb, f1W, f1b, s1W, s1b,
                                          h, D, Sh, N);
        scatter_bins<<<seb, TB, 0, stream>>>(ei, attr, cursors, lists, ovf, ovfh,
                                             E, nbins, cap);

        gather_bins<<<nbins, 256, 0, stream>>>(cursors, lists, cap, D, Sh,
                                               f1W, s1W, acc, N, nbins);
        ovf_pass<<<256, 256, 0, stream>>>(ovf, ovfh, D, Sh, f1W, s1W, acc);
        node_mid_h<<<nb, TB, 0, stream>>>(h, acc, f2W, f2b, s2W, s2b, D, Sh, N);

        gather_bins<<<nbins, 256, 0, stream>>>(cursors, lists, cap, D, Sh,
                                               f2W, s2W, acc, N, nbins);
        ovf_pass<<<256, 256, 0, stream>>>(ovf, ovfh, D, Sh, f2W, s2W, acc);
        node_pool<<<nb, TB, 0, stream>>>(h, acc, batch, gsum, gcnt, N);
        mlp_head<<<G, 128, 0, stream>>>(gsum, gcnt, fc1W, fc1b, fc2W, fc2b,
                                        outW, outb, (float*)d_out, G);
    } else {
        // ===== fallback: fp32 atomic path =====
        size_t o = 0;
        float* fh    = ws + o; o += (size_t)N * DH;
        float* agg   = ws + o; o += (size_t)N * DH;
        float* fD    = ws + o; o += (size_t)N * REC;
        float* fS    = ws + o; o += (size_t)N * REC;
        float* fgsum = ws + o; o += (size_t)G * DH;
        float* fgcnt = ws + o; o += G;

        const int eb = (E + TB - 1) / TB;
        node_pre_f32<<<nb, TB, 0, stream>>>(x, preW, preb, f1W, f1b, s1W, s1b,
                                            fh, fD, fS, agg, fgsum, fgcnt, N, G);
        edge_pass<<<eb, TB, 0, stream>>>(ei, attr, fD, fS, f1W, s1W, agg, E);
        node_mid<<<nb, TB, 0, stream>>>(fh, agg, f2W, f2b, s2W, s2b, fD, fS, N);
        edge_pass<<<eb, TB, 0, stream>>>(ei, attr, fD, fS, f2W, s2W, agg, E);
        node_post<<<nb, TB, 0, stream>>>(fh, agg, batch, fgsum, fgcnt, N);
        mlp_head<<<G, 128, 0, stream>>>(fgsum, fgcnt, fc1W, fc1b, fc2W, fc2b,
                                        outW, outb, (float*)d_out, G);
    }
}

// Round 6
// 956.208 us; speedup vs baseline: 1.5024x; 1.3925x over previous
//
#include <hip/hip_runtime.h>
#include <hip/hip_bf16.h>
#include <hip/hip_fp16.h>
#include <math.h>

#define DH 10      // hidden dim
#define DE 3       // edge attr dim
#define DIN 3      // input dim
#define REC 20     // fp32 D record: 20 floats = 80B
#define SHU 16     // fp16 S record stride in uints: 64B-ALIGNED (10 used) -> 1 line/record
#define VEC 4      // lanes cooperating per node in gather
#define SSH 15     // slice shift
#define NS 6       // slices 0..5 (slice 5 merged tail); slice = 32768*64B = 2MB (L2-resident)
#define WGN 1280   // persistent workgroups (5/CU x 256 CUs, all co-resident; LDS 30KB*5=150KB)
#define MAXNPW 256 // max dst nodes per workgroup (LDS sizing)
#define HPAD 4     // heads cursor stride (4 cursors/64B line; R0 was 16/line @ ~85 edges/line)
#define OVFCAP (1 << 20)   // overflow side-list capacity (1M recs, 16MB)
#define PBIN 16    // graph bins per pooling block (256 sorted nodes span <= ~4)

typedef unsigned int u32;
typedef u32 u2v __attribute__((ext_vector_type(2)));

__device__ __forceinline__ u32 pack_h2(float a, float b) {
    union { __half2 h; u32 u; } cv;
    cv.h = __floats2half2_rn(a, b);
    return cv.u;
}
__device__ __forceinline__ float2 unpack_h2(u32 u) {
    union { u32 u; __half2 h; } cv; cv.u = u;
    return __half22float2(cv.h);
}

// ---------------------------------------------------------------------------
// Per-node records. D (fp32, dst side, biases folded). S (fp16 packed).
// ---------------------------------------------------------------------------
__device__ __forceinline__ void compute_records_h(
    const float* __restrict__ hh,
    const float* __restrict__ fW, const float* __restrict__ fb,
    const float* __restrict__ sW, const float* __restrict__ sb,
    float* __restrict__ Dout, u32* __restrict__ Sout)
{
    float fsv[DH], ssv[DH];
#pragma unroll
    for (int j = 0; j < DH; ++j) {
        float fd = fb[j], sd = sb[j], fs = 0.f, ss = 0.f;
#pragma unroll
        for (int k = 0; k < DH; ++k) {
            fd += hh[k] * fW[j*23 + k];
            fs += hh[k] * fW[j*23 + 10 + k];
            sd += hh[k] * sW[j*23 + k];
            ss += hh[k] * sW[j*23 + 10 + k];
        }
        Dout[j]      = fd;
        Dout[DH + j] = sd;
        fsv[j] = fs;
        ssv[j] = ss;
    }
#pragma unroll
    for (int j = 0; j < 5; ++j) {
        Sout[j]     = pack_h2(fsv[2*j], fsv[2*j+1]);
        Sout[5 + j] = pack_h2(ssv[2*j], ssv[2*j+1]);
    }
}

// fp32 variant for the fallback path
__device__ __forceinline__ void compute_records(
    const float* __restrict__ hh,
    const float* __restrict__ fW, const float* __restrict__ fb,
    const float* __restrict__ sW, const float* __restrict__ sb,
    float* __restrict__ Dout, float* __restrict__ Sout)
{
#pragma unroll
    for (int j = 0; j < DH; ++j) {
        float fd = fb[j], sd = sb[j], fs = 0.f, ss = 0.f;
#pragma unroll
        for (int k = 0; k < DH; ++k) {
            fd += hh[k] * fW[j*23 + k];
            fs += hh[k] * fW[j*23 + 10 + k];
            sd += hh[k] * sW[j*23 + k];
            ss += hh[k] * sW[j*23 + 10 + k];
        }
        Dout[j]      = fd;
        Dout[DH + j] = sd;
        Sout[j]      = fs;
        Sout[DH + j] = ss;
    }
}

// ---------------------------------------------------------------------------
__global__ void zero_small(int* __restrict__ heads, int M4, int* __restrict__ ovfh,
                           float* __restrict__ gsum, float* __restrict__ gcnt, int G)
{
    int i = blockIdx.x * blockDim.x + threadIdx.x;
    if (i < M4) heads[i] = 0;
    if (i == 0) *ovfh = 0;
    if (i < G * DH) gsum[i] = 0.f;
    if (i < G) gcnt[i] = 0.f;
}

// ---------------------------------------------------------------------------
// P0: h0 = relu(x@preW.T+preb); layer-1 records
// ---------------------------------------------------------------------------
__global__ void node_pre_h(const float* __restrict__ x,
                           const float* __restrict__ preW, const float* __restrict__ preb,
                           const float* __restrict__ fW, const float* __restrict__ fb,
                           const float* __restrict__ sW, const float* __restrict__ sb,
                           float* __restrict__ h, float* __restrict__ D, u32* __restrict__ Sh,
                           int N)
{
    __shared__ float lpW[30], lpb[10], lfW[230], lfb[10], lsW[230], lsb[10];
    for (int i = threadIdx.x; i < 30;  i += blockDim.x) lpW[i] = preW[i];
    for (int i = threadIdx.x; i < 10;  i += blockDim.x) { lpb[i] = preb[i]; lfb[i] = fb[i]; lsb[i] = sb[i]; }
    for (int i = threadIdx.x; i < 230; i += blockDim.x) { lfW[i] = fW[i]; lsW[i] = sW[i]; }
    __syncthreads();

    int n = blockIdx.x * blockDim.x + threadIdx.x;
    if (n >= N) return;

    float x0 = x[(size_t)n*3], x1 = x[(size_t)n*3+1], x2 = x[(size_t)n*3+2];
    float hh[DH];
#pragma unroll
    for (int j = 0; j < DH; ++j)
        hh[j] = fmaxf(lpb[j] + x0*lpW[j*3] + x1*lpW[j*3+1] + x2*lpW[j*3+2], 0.f);

    float* hp = h + (size_t)n * DH;
#pragma unroll
    for (int j = 0; j < DH; ++j) hp[j] = hh[j];

    compute_records_h(hh, lfW, lfb, lsW, lsb, D + (size_t)n*REC, Sh + (size_t)n*SHU);
}

// ---------------------------------------------------------------------------
// One-pass scatter into capacity buckets keyed (slice, node). R0-proven form;
// ONLY change: heads cursors padded to stride HPAD=4 (4/line vs 16/line) to
// probe whether coherence-point line contention is a scatter component.
// Edge rec 8B: w0 = src(18) | a2q(14)<<18 ; w1 = h2(a0,a1).
// ---------------------------------------------------------------------------
__global__ void scatter_cap(const int* __restrict__ ei, const float* __restrict__ attr,
                            int* __restrict__ heads, uint2* __restrict__ csr,
                            uint4* __restrict__ ovf, int* __restrict__ ovfh,
                            int E, int N, int cap)
{
    int e = blockIdx.x * blockDim.x + threadIdx.x;
    if (e >= E) return;
    int src = __builtin_nontemporal_load(ei + e);
    int dst = __builtin_nontemporal_load(ei + (size_t)E + e);
    float a0 = __builtin_nontemporal_load(attr + (size_t)e * DE);
    float a1 = __builtin_nontemporal_load(attr + (size_t)e * DE + 1);
    float a2 = __builtin_nontemporal_load(attr + (size_t)e * DE + 2);
    int p = src >> SSH; if (p > NS - 1) p = NS - 1;
    u32 a2q = (u32)(fminf(fmaxf(a2, 0.f), 1.0f) * 16383.0f + 0.5f);
    u32 w0 = (u32)src | (a2q << 18);
    u32 w1 = pack_h2(a0, a1);

    size_t idx = (size_t)p * N + dst;
    int pos = atomicAdd(&heads[idx * HPAD], 1);
    if (pos < cap) {
        csr[idx * cap + pos] = make_uint2(w0, w1);
    } else {
        int op = atomicAdd(ovfh, 1);
        if (op < OVFCAP) ovf[op] = make_uint4((u32)dst, w0, w1, 0u);
    }
}

// ---------------------------------------------------------------------------
// Persistent gather (R0-proven, verbatim except heads stride): each wg owns
// npw dst nodes; drec+acc in LDS; walks src slices in lockstep (all 1280 wgs
// co-resident at 5 blk/CU -> slice S-records stay L2-resident).
// ---------------------------------------------------------------------------
__global__ __launch_bounds__(256, 5) void gather_persist(
    const int* __restrict__ heads, const uint2* __restrict__ csr, int cap,
    const float* __restrict__ D, const u32* __restrict__ ShU,
    const float* __restrict__ Wf, const float* __restrict__ Ws,
    float* __restrict__ accg, int N, int npw)
{
    __shared__ float s_drec[MAXNPW * REC];   // 20 KB
    __shared__ float s_acc[MAXNPW * DH];     // 10 KB

    int base = blockIdx.x * npw;
    if (base >= N) return;
    int cn = N - base; if (cn > npw) cn = npw;

    for (int i = threadIdx.x; i < cn * REC; i += 256)
        s_drec[i] = __builtin_nontemporal_load(D + (size_t)base * REC + i);
    for (int i = threadIdx.x; i < cn * DH; i += 256)
        s_acc[i] = 0.f;

    float wf[30], wsr[30];   // wave-uniform -> SGPRs
#pragma unroll
    for (int i = 0; i < 30; ++i) {
        int j = i / 3, t = i % 3;
        wf[i]  = Wf[j*23 + 20 + t];
        wsr[i] = Ws[j*23 + 20 + t];
    }
    __syncthreads();

    int g   = threadIdx.x >> 2;       // lane-group (node within chunk)
    int sub = threadIdx.x & (VEC - 1);
    int nchunk = (cn + 63) >> 6;

    for (int p = 0; p < NS; ++p) {
        for (int c = 0; c < nchunk; ++c) {
            int nl = (c << 6) + g;
            if (nl < cn) {
                size_t idx = (size_t)p * N + (base + nl);
                int cnt = heads[idx * HPAD]; if (cnt > cap) cnt = cap;

                float partial[DH];
#pragma unroll
                for (int j = 0; j < DH; ++j) partial[j] = 0.f;

                if (cnt > 0) {
                    float dr[REC];
#pragma unroll
                    for (int j = 0; j < REC; ++j) dr[j] = s_drec[nl*REC + j];

                    size_t rb = idx * cap;
                    for (int q = sub; q < cnt; q += VEC) {
                        u2v c2 = __builtin_nontemporal_load(((const u2v*)csr) + rb + q);
                        u32 w0 = c2.x;
                        int src = (int)(w0 & 0x3FFFFu);
                        float a2 = (float)(w0 >> 18) * (1.0f / 16383.0f);
                        float2 a01 = unpack_h2(c2.y);
                        float a0 = a01.x, a1 = a01.y;

                        const uint4* sp = (const uint4*)(ShU + (size_t)src * SHU);
                        uint4 A = sp[0];
                        uint4 B = sp[1];
                        uint2 C = *(const uint2*)(sp + 2);
                        u32 u[10] = {A.x, A.y, A.z, A.w, B.x, B.y, B.z, B.w, C.x, C.y};
                        float s[20];
#pragma unroll
                        for (int i = 0; i < 10; ++i) {
                            float2 f = unpack_h2(u[i]);
                            s[2*i] = f.x; s[2*i+1] = f.y;
                        }
#pragma unroll
                        for (int j = 0; j < DH; ++j) {
                            float pf = dr[j]      + s[j]      + a0*wf[j*3]  + a1*wf[j*3+1]  + a2*wf[j*3+2];
                            float ps = dr[DH + j] + s[DH + j] + a0*wsr[j*3] + a1*wsr[j*3+1] + a2*wsr[j*3+2];
                            float sg  = __builtin_amdgcn_rcpf(1.0f + __expf(-pf));           // sigmoid
                            float sp2 = fmaxf(ps, 0.f) + __logf(1.0f + __expf(-fabsf(ps)));  // softplus
                            partial[j] += sg * sp2;
                        }
                    }
                }
#pragma unroll
                for (int j = 0; j < DH; ++j) {
                    partial[j] += __shfl_xor(partial[j], 1);
                    partial[j] += __shfl_xor(partial[j], 2);
                }
                if (sub == 0 && cnt > 0) {
#pragma unroll
                    for (int j = 0; j < DH; ++j) s_acc[nl*DH + j] += partial[j];
                }
            }
        }
        __syncthreads();   // keep the wg's waves slice-aligned
    }

    for (int i = threadIdx.x; i < cn * DH; i += 256)
        accg[(size_t)base * DH + i] = s_acc[i];
}

// ---------------------------------------------------------------------------
// Overflow pass (runs after gather_persist): ~1e4 edges, global atomics.
// ---------------------------------------------------------------------------
__global__ void ovf_pass(const uint4* __restrict__ ovf, const int* __restrict__ ovfh,
                         const float* __restrict__ D, const u32* __restrict__ ShU,
                         const float* __restrict__ Wf, const float* __restrict__ Ws,
                         float* __restrict__ accg)
{
    __shared__ float wf[30], wsr[30];
    if (threadIdx.x < 30) {
        int j = threadIdx.x / 3, t = threadIdx.x % 3;
        wf[threadIdx.x]  = Wf[j*23 + 20 + t];
        wsr[threadIdx.x] = Ws[j*23 + 20 + t];
    }
    __syncthreads();

    int oc = *ovfh; if (oc > OVFCAP) oc = OVFCAP;
    for (int i = blockIdx.x * blockDim.x + threadIdx.x; i < oc;
         i += gridDim.x * blockDim.x) {
        uint4 e = ovf[i];
        int dst = (int)e.x;
        u32 w0 = e.y;
        int src = (int)(w0 & 0x3FFFFu);
        float a2 = (float)(w0 >> 18) * (1.0f / 16383.0f);
        float2 a01 = unpack_h2(e.z);
        float a0 = a01.x, a1 = a01.y;

        float dr[REC];
        const float4* dp = (const float4*)(D + (size_t)dst * REC);
#pragma unroll
        for (int k = 0; k < 5; ++k) ((float4*)dr)[k] = dp[k];

        const uint4* sp = (const uint4*)(ShU + (size_t)src * SHU);
        uint4 A = sp[0];
        uint4 B = sp[1];
        uint2 C = *(const uint2*)(sp + 2);
        u32 u[10] = {A.x, A.y, A.z, A.w, B.x, B.y, B.z, B.w, C.x, C.y};
        float s[20];
#pragma unroll
        for (int k = 0; k < 10; ++k) {
            float2 f = unpack_h2(u[k]);
            s[2*k] = f.x; s[2*k+1] = f.y;
        }
        float* ap = accg + (size_t)dst * DH;
#pragma unroll
        for (int j = 0; j < DH; ++j) {
            float pf = dr[j]      + s[j]      + a0*wf[j*3]  + a1*wf[j*3+1]  + a2*wf[j*3+2];
            float ps = dr[DH + j] + s[DH + j] + a0*wsr[j*3] + a1*wsr[j*3+1] + a2*wsr[j*3+2];
            float sg  = __builtin_amdgcn_rcpf(1.0f + __expf(-pf));
            float sp2 = fmaxf(ps, 0.f) + __logf(1.0f + __expf(-fabsf(ps)));
            atomicAdd(ap + j, sg * sp2);
        }
    }
}

// ---------------------------------------------------------------------------
// Layer-1 epilogue: h = relu(h + acc); records for layer 2
// ---------------------------------------------------------------------------
__global__ void node_mid_h(float* __restrict__ h, const float* __restrict__ acc,
                           const float* __restrict__ fW, const float* __restrict__ fb,
                           const float* __restrict__ sW, const float* __restrict__ sb,
                           float* __restrict__ D, u32* __restrict__ Sh, int N)
{
    __shared__ float lfW[230], lfb[10], lsW[230], lsb[10];
    for (int i = threadIdx.x; i < 230; i += blockDim.x) { lfW[i] = fW[i]; lsW[i] = sW[i]; }
    for (int i = threadIdx.x; i < 10;  i += blockDim.x) { lfb[i] = fb[i]; lsb[i] = sb[i]; }
    __syncthreads();
    int n = blockIdx.x * blockDim.x + threadIdx.x;
    if (n >= N) return;
    float* hp = h + (size_t)n * DH;
    const float* ap = acc + (size_t)n * DH;
    float hh[DH];
#pragma unroll
    for (int j = 0; j < DH; ++j) {
        hh[j] = fmaxf(hp[j] + ap[j], 0.f);
        hp[j] = hh[j];
    }
    compute_records_h(hh, lfW, lfb, lsW, lsb, D + (size_t)n*REC, Sh + (size_t)n*SHU);
}

// ---------------------------------------------------------------------------
// Layer-2 epilogue + pooling: segmented block-local reduction (batch sorted).
// ---------------------------------------------------------------------------
__global__ void node_pool(const float* __restrict__ h, const float* __restrict__ acc,
                          const int* __restrict__ batch,
                          float* __restrict__ gsum, float* __restrict__ gcnt, int N)
{
    __shared__ float lg[PBIN * DH];
    __shared__ float lc[PBIN];

    int base = blockIdx.x * blockDim.x;
    int n = base + threadIdx.x;

    for (int i = threadIdx.x; i < PBIN * DH; i += blockDim.x) lg[i] = 0.f;
    if (threadIdx.x < PBIN) lc[threadIdx.x] = 0.f;
    __syncthreads();

    int b0 = batch[base];   // uniform across block (sorted)

    if (n < N) {
        int b = batch[n];
        int off = b - b0;
        const float* hp = h + (size_t)n * DH;
        const float* ap = acc + (size_t)n * DH;
        float v[DH];
#pragma unroll
        for (int j = 0; j < DH; ++j) v[j] = fmaxf(hp[j] + ap[j], 0.f);

        if (off < PBIN) {
#pragma unroll
            for (int j = 0; j < DH; ++j) atomicAdd(&lg[off * DH + j], v[j]);
            atomicAdd(&lc[off], 1.f);
        } else {   // statistically impossible (256 sorted nodes span ~4 graphs)
            float* gp = gsum + (size_t)b * DH;
#pragma unroll
            for (int j = 0; j < DH; ++j) atomicAdd(gp + j, v[j]);
            atomicAdd(gcnt + b, 1.f);
        }
    }
    __syncthreads();

    for (int i = threadIdx.x; i < PBIN * DH; i += blockDim.x) {
        int g = i / DH;
        if (lc[g] > 0.f)
            atomicAdd(&gsum[(size_t)(b0 + g) * DH + (i - g * DH)], lg[i]);
    }
    if (threadIdx.x < PBIN && lc[threadIdx.x] > 0.f)
        atomicAdd(&gcnt[b0 + threadIdx.x], lc[threadIdx.x]);
}

// ---------------------------------------------------------------------------
// Fallback path kernels (fp32 atomic path; used only if ws too small / N too big)
// ---------------------------------------------------------------------------
__global__ void node_pre_f32(const float* __restrict__ x,
                             const float* __restrict__ preW, const float* __restrict__ preb,
                             const float* __restrict__ fW, const float* __restrict__ fb,
                             const float* __restrict__ sW, const float* __restrict__ sb,
                             float* __restrict__ h, float* __restrict__ D, float* __restrict__ S,
                             float* __restrict__ agg,
                             float* __restrict__ gsum, float* __restrict__ gcnt, int N, int G)
{
    __shared__ float lpW[30], lpb[10], lfW[230], lfb[10], lsW[230], lsb[10];
    for (int i = threadIdx.x; i < 30;  i += blockDim.x) lpW[i] = preW[i];
    for (int i = threadIdx.x; i < 10;  i += blockDim.x) { lpb[i] = preb[i]; lfb[i] = fb[i]; lsb[i] = sb[i]; }
    for (int i = threadIdx.x; i < 230; i += blockDim.x) { lfW[i] = fW[i]; lsW[i] = sW[i]; }
    __syncthreads();
    int n = blockIdx.x * blockDim.x + threadIdx.x;
    if (n < G * DH) gsum[n] = 0.f;
    if (n < G)      gcnt[n] = 0.f;
    if (n >= N) return;
    float x0 = x[(size_t)n*3], x1 = x[(size_t)n*3+1], x2 = x[(size_t)n*3+2];
    float hh[DH];
#pragma unroll
    for (int j = 0; j < DH; ++j)
        hh[j] = fmaxf(lpb[j] + x0*lpW[j*3] + x1*lpW[j*3+1] + x2*lpW[j*3+2], 0.f);
    float* hp = h + (size_t)n * DH;
    float* ap = agg + (size_t)n * DH;
#pragma unroll
    for (int j = 0; j < DH; ++j) { hp[j] = hh[j]; ap[j] = 0.f; }
    compute_records(hh, lfW, lfb, lsW, lsb, D + (size_t)n*REC, S + (size_t)n*REC);
}

__global__ void edge_pass(const int* __restrict__ ei, const float* __restrict__ attr,
                          const float* __restrict__ D, const float* __restrict__ S,
                          const float* __restrict__ Wf, const float* __restrict__ Ws,
                          float* __restrict__ agg, int E)
{
    __shared__ float wfe[30], wse[30];
    if (threadIdx.x < 30) {
        int j = threadIdx.x / 3, t = threadIdx.x % 3;
        wfe[threadIdx.x] = Wf[j*23 + 20 + t];
        wse[threadIdx.x] = Ws[j*23 + 20 + t];
    }
    __syncthreads();
    int e = blockIdx.x * blockDim.x + threadIdx.x;
    if (e >= E) return;
    int src = ei[e];
    int dst = ei[(size_t)E + e];
    const float* eap = attr + (size_t)e * DE;
    float ea0 = eap[0], ea1 = eap[1], ea2 = eap[2];
    float drec[REC], srec[REC];
    const float4* Dp = (const float4*)(D + (size_t)dst * REC);
    const float4* Sp = (const float4*)(S + (size_t)src * REC);
#pragma unroll
    for (int i = 0; i < 5; ++i) { ((float4*)drec)[i] = Dp[i]; ((float4*)srec)[i] = Sp[i]; }
    float* ap = agg + (size_t)dst * DH;
#pragma unroll
    for (int j = 0; j < DH; ++j) {
        float pf = drec[j]      + srec[j]      + ea0*wfe[j*3] + ea1*wfe[j*3+1] + ea2*wfe[j*3+2];
        float ps = drec[DH + j] + srec[DH + j] + ea0*wse[j*3] + ea1*wse[j*3+1] + ea2*wse[j*3+2];
        float sg = 1.0f / (1.0f + __expf(-pf));
        float sp = fmaxf(ps, 0.f) + log1pf(__expf(-fabsf(ps)));
        atomicAdd(ap + j, sg * sp);
    }
}

__global__ void node_mid(float* __restrict__ h, float* __restrict__ agg,
                         const float* __restrict__ fW, const float* __restrict__ fb,
                         const float* __restrict__ sW, const float* __restrict__ sb,
                         float* __restrict__ D, float* __restrict__ S, int N)
{
    __shared__ float lfW[230], lfb[10], lsW[230], lsb[10];
    for (int i = threadIdx.x; i < 230; i += blockDim.x) { lfW[i] = fW[i]; lsW[i] = sW[i]; }
    for (int i = threadIdx.x; i < 10;  i += blockDim.x) { lfb[i] = fb[i]; lsb[i] = sb[i]; }
    __syncthreads();
    int n = blockIdx.x * blockDim.x + threadIdx.x;
    if (n >= N) return;
    float* hp = h + (size_t)n * DH;
    float* ap = agg + (size_t)n * DH;
    float hh[DH];
#pragma unroll
    for (int j = 0; j < DH; ++j) {
        hh[j] = fmaxf(hp[j] + ap[j], 0.f);
        hp[j] = hh[j];
        ap[j] = 0.f;
    }
    compute_records(hh, lfW, lfb, lsW, lsb, D + (size_t)n*REC, S + (size_t)n*REC);
}

__global__ void node_post(const float* __restrict__ h, const float* __restrict__ agg,
                          const int* __restrict__ batch,
                          float* __restrict__ gsum, float* __restrict__ gcnt, int N)
{
    int n = blockIdx.x * blockDim.x + threadIdx.x;
    if (n >= N) return;
    int b = batch[n];
    const float* hp = h + (size_t)n * DH;
    const float* ap = agg + (size_t)n * DH;
    float* gp = gsum + (size_t)b * DH;
#pragma unroll
    for (int j = 0; j < DH; ++j)
        atomicAdd(gp + j, fmaxf(hp[j] + ap[j], 0.f));
    atomicAdd(gcnt + b, 1.f);
}

// ---------------------------------------------------------------------------
// MLP head: one block (128 threads) per graph.
// ---------------------------------------------------------------------------
__global__ void mlp_head(const float* __restrict__ gsum, const float* __restrict__ gcnt,
                         const float* __restrict__ fc1W, const float* __restrict__ fc1b,
                         const float* __restrict__ fc2W, const float* __restrict__ fc2b,
                         const float* __restrict__ outW, const float* __restrict__ outb,
                         float* __restrict__ out, int G)
{
    __shared__ float g[DH], a1[128], a2[128];
    int gid = blockIdx.x;
    int t = threadIdx.x;
    if (t < DH) {
        float c = fmaxf(gcnt[gid], 1.0f);
        g[t] = gsum[(size_t)gid*DH + t] / c;
    }
    __syncthreads();
    {
        float acc = fc1b[t];
        const float* w = fc1W + (size_t)t * DH;
#pragma unroll
        for (int k = 0; k < DH; ++k) acc += w[k] * g[k];
        a1[t] = fmaxf(acc, 0.f);
    }
    __syncthreads();
    {
        float acc = fc2b[t];
        const float* w = fc2W + (size_t)t * 128;
#pragma unroll 8
        for (int k = 0; k < 128; ++k) acc += w[k] * a1[k];
        a2[t] = fmaxf(acc, 0.f);
    }
    __syncthreads();
    if (t < 3) {
        float acc = outb[t];
        const float* w = outW + (size_t)t * 128;
#pragma unroll 8
        for (int k = 0; k < 128; ++k) acc += w[k] * a2[k];
        out[(size_t)gid*3 + t] = acc;
    }
}

// ---------------------------------------------------------------------------
extern "C" void kernel_launch(void* const* d_in, const int* in_sizes, int n_in,
                              void* d_out, int out_size, void* d_ws, size_t ws_size,
                              hipStream_t stream)
{
    const float* x     = (const float*)d_in[0];
    const int*   ei    = (const int*)  d_in[1];
    const float* attr  = (const float*)d_in[2];
    const int*   batch = (const int*)  d_in[3];
    const float* preW  = (const float*)d_in[4];
    const float* preb  = (const float*)d_in[5];
    const float* f1W   = (const float*)d_in[6];
    const float* f1b   = (const float*)d_in[7];
    const float* s1W   = (const float*)d_in[8];
    const float* s1b   = (const float*)d_in[9];
    const float* f2W   = (const float*)d_in[10];
    const float* f2b   = (const float*)d_in[11];
    const float* s2W   = (const float*)d_in[12];
    const float* s2b   = (const float*)d_in[13];
    const float* fc1W  = (const float*)d_in[14];
    const float* fc1b  = (const float*)d_in[15];
    const float* fc2W  = (const float*)d_in[16];
    const float* fc2b  = (const float*)d_in[17];
    const float* outW  = (const float*)d_in[18];
    const float* outb  = (const float*)d_in[19];

    const int N = in_sizes[0] / DIN;          // 200000
    const int E = in_sizes[1] / 2;            // 6400000
    const int G = out_size / 3;               // 1024
    const int M = NS * N;                     // bucket-head table size (logical)
    const int M4 = M * HPAD;                  // padded cursor array size
    const int npw = (N + WGN - 1) / WGN;      // 157 dst nodes per persistent wg

    const int TB = 256;
    const int nb = (N + TB - 1) / TB;
    const int eb = (E + TB - 1) / TB;
    const int zb = ((M4 > G * DH ? M4 : G * DH) + TB - 1) / TB;

    // ---- workspace layout (csr capacity computed from remaining budget) ----
    size_t f_off = 0;
    float* ws = (float*)d_ws;
    float* h    = ws + f_off; f_off += (size_t)N * DH;
    float* D    = ws + f_off; f_off += (size_t)N * REC;
    f_off = (f_off + 15) & ~(size_t)15;                        // 64B-align Sh
    u32*   Sh   = (u32*)(ws + f_off); f_off += (size_t)N * SHU;
    float* acc  = ws + f_off; f_off += (size_t)N * DH;
    float* gsum = ws + f_off; f_off += (size_t)G * DH;
    float* gcnt = ws + f_off; f_off += G;
    f_off = (f_off + 15) & ~(size_t)15;
    int* heads  = (int*)(ws + f_off); f_off += (size_t)M4;
    int* ovfh   = (int*)(ws + f_off); f_off += 1;
    f_off = (f_off + 15) & ~(size_t)15;
    uint4* ovf  = (uint4*)(ws + f_off); f_off += (size_t)OVFCAP * 4;
    f_off = (f_off + 15) & ~(size_t)15;
    uint2* csr  = (uint2*)(ws + f_off);

    size_t core_bytes = f_off * sizeof(float);
    long long budget = (long long)ws_size - (long long)core_bytes;
    int cap = 0;
    if (budget > 0) cap = (int)(budget / ((long long)M * 8));
    if (cap > 16) cap = 16;

    if (cap >= 6 && npw <= MAXNPW && N < (1 << 18)) {
        // ===== capacity-bucket + persistent slice-walk path (R0-proven) =====
        zero_small<<<zb, TB, 0, stream>>>(heads, M4, ovfh, gsum, gcnt, G);
        node_pre_h<<<nb, TB, 0, stream>>>(x, preW, preb, f1W, f1b, s1W, s1b,
                                          h, D, Sh, N);
        scatter_cap<<<eb, TB, 0, stream>>>(ei, attr, heads, csr, ovf, ovfh, E, N, cap);

        gather_persist<<<WGN, 256, 0, stream>>>(heads, csr, cap, D, Sh,
                                                f1W, s1W, acc, N, npw);
        ovf_pass<<<256, 256, 0, stream>>>(ovf, ovfh, D, Sh, f1W, s1W, acc);
        node_mid_h<<<nb, TB, 0, stream>>>(h, acc, f2W, f2b, s2W, s2b, D, Sh, N);

        gather_persist<<<WGN, 256, 0, stream>>>(heads, csr, cap, D, Sh,
                                                f2W, s2W, acc, N, npw);
        ovf_pass<<<256, 256, 0, stream>>>(ovf, ovfh, D, Sh, f2W, s2W, acc);
        node_pool<<<nb, TB, 0, stream>>>(h, acc, batch, gsum, gcnt, N);
        mlp_head<<<G, 128, 0, stream>>>(gsum, gcnt, fc1W, fc1b, fc2W, fc2b,
                                        outW, outb, (float*)d_out, G);
    } else {
        // ===== fallback: fp32 atomic path =====
        size_t o = 0;
        float* fh    = ws + o; o += (size_t)N * DH;
        float* agg   = ws + o; o += (size_t)N * DH;
        float* fD    = ws + o; o += (size_t)N * REC;
        float* fS    = ws + o; o += (size_t)N * REC;
        float* fgsum = ws + o; o += (size_t)G * DH;
        float* fgcnt = ws + o; o += G;

        node_pre_f32<<<nb, TB, 0, stream>>>(x, preW, preb, f1W, f1b, s1W, s1b,
                                            fh, fD, fS, agg, fgsum, fgcnt, N, G);
        edge_pass<<<eb, TB, 0, stream>>>(ei, attr, fD, fS, f1W, s1W, agg, E);
        node_mid<<<nb, TB, 0, stream>>>(fh, agg, f2W, f2b, s2W, s2b, fD, fS, N);
        edge_pass<<<eb, TB, 0, stream>>>(ei, attr, fD, fS, f2W, s2W, agg, E);
        node_post<<<nb, TB, 0, stream>>>(fh, agg, batch, fgsum, fgcnt, N);
        mlp_head<<<G, 128, 0, stream>>>(fgsum, fgcnt, fc1W, fc1b, fc2W, fc2b,
                                        outW, outb, (float*)d_out, G);
    }
}